// Round 4
// baseline (963.118 us; speedup 1.0000x reference)
//
#include <hip/hip_runtime.h>

// Problem constants
#define BB   4
#define CIN  64
#define HH   256
#define WW   256
#define QQ   256
#define KK   16

typedef _Float16 half8 __attribute__((ext_vector_type(8)));
typedef float   f32x16 __attribute__((ext_vector_type(16)));
typedef unsigned int u32;

// ---- workspace layout (bytes); r8 proved ws_size >= 169378048 ----
#define OFF_W1R   0ull
#define OFF_W2R   294912ull
#define OFF_WMU   1474560ull
#define OFF_LGB   1490944ull
#define OFF_ACT0  1605888ull
#define OFF_ACT1  35160320ull

__device__ __forceinline__ void dma16(const void* g, void* l) {
  __builtin_amdgcn_global_load_lds(
      (const __attribute__((address_space(1))) u32*)g,
      (__attribute__((address_space(3))) u32*)l, 16, 0, 0);
}

// ---------------------------------------------------------------------------
// Prep. Blocks 0..575: w1r; 576..2879: w2r; 2880..3007: wmu2 partials;
// 3008..3023: lgb. Weight image block (cc,tt)=16KB: 256 rows x 32ch;
// 16B-quarter q of row n stored at slot q^((n>>1)&3).
// ---------------------------------------------------------------------------
__global__ __launch_bounds__(256) void k_prep(
    const float* __restrict__ w1, const float* __restrict__ w2,
    const float* __restrict__ w3, const float* __restrict__ b3,
    const float* __restrict__ mu,
    _Float16* __restrict__ w1r, _Float16* __restrict__ w2r,
    float* __restrict__ wpart, float* __restrict__ lgb) {
  int bid = blockIdx.x, tid = threadIdx.x;
  if (bid < 576) {                          // w1r (CI=64)
    int idx = bid * 256 + tid;
    int blk = idx >> 13;
    int cc = blk / 9, tt = blk - cc * 9;
    int rem = idx & 8191;
    int n = rem >> 5, r = rem & 31;
    int q = (r >> 3) ^ ((n >> 1) & 3), e = r & 7;
    int c = cc * 32 + q * 8 + e;
    w1r[idx] = (_Float16)w1[(n * 64 + c) * 9 + tt];
  } else if (bid < 2880) {                  // w2r (CI=256)
    int d = (bid - 576) * 256 + tid;
    int blk = d >> 13;
    int cc = blk / 9, tt = blk - cc * 9;
    int rem = d & 8191;
    int n = rem >> 5, r = rem & 31;
    int q = (r >> 3) ^ ((n >> 1) & 3), e = r & 7;
    int c = cc * 32 + q * 8 + e;
    w2r[d] = (_Float16)w2[(n * 256 + c) * 9 + tt];
  } else if (bid < 3008) {                  // wmu2 partials
    int j = bid - 2880;
    int k = j >> 3, o0 = (j & 7) << 5;
    float s = 0.f;
#pragma unroll 4
    for (int oi = 0; oi < 32; ++oi) {
      int o = o0 + oi;
      s = fmaf(mu[k * 256 + o], w3[o * 256 + tid], s);
    }
    wpart[j * 256 + tid] = s;
  } else {                                  // lgb, one block per k
    int k = bid - 3008;
    float m = mu[k * 256 + tid];
    __shared__ float red[256];
    red[tid] = m * (2.f * b3[tid] - m);
    __syncthreads();
    for (int st = 128; st > 0; st >>= 1) {
      if (tid < st) red[tid] += red[tid + st];
      __syncthreads();
    }
    if (tid == 0) lgb[k] = red[0];
  }
}

// Reduce wmu2 partials: wmu2[k][c] = 2 * sum_p wpart[k*8+p][c]. 16 blocks.
__global__ __launch_bounds__(256) void k_prep2(
    const float* __restrict__ wpart, float* __restrict__ wmu2) {
  int k = blockIdx.x, tid = threadIdx.x;
  float s = 0.f;
#pragma unroll
  for (int p = 0; p < 8; ++p) s += wpart[(k * 8 + p) * 256 + tid];
  wmu2[k * 256 + tid] = 2.f * s;
}

// ---------------------------------------------------------------------------
// T0: x NCHW fp32 -> act0 [b][HW][64] fp16, all 4 batches. grid 4096.
// ---------------------------------------------------------------------------
__global__ __launch_bounds__(256) void k_t0(const float* __restrict__ x,
                                            _Float16* __restrict__ act0) {
  __shared__ float tile[64][65];
  int blk = blockIdx.x;
  int b = blk >> 10;
  int p0 = (blk & 1023) << 6;
  int t = threadIdx.x;
  {
    int p = t & 63, c0 = t >> 6;
    const float* xb = x + (size_t)b * (CIN * 65536) + p0 + p;
#pragma unroll
    for (int i = 0; i < 16; ++i) {
      int c = c0 + (i << 2);
      tile[c][p] = xb[(size_t)c * 65536];
    }
  }
  __syncthreads();
  {
    _Float16* o = act0 + (size_t)(b * 65536 + p0) * CIN;
#pragma unroll
    for (int uu = 0; uu < 2; ++uu) {
      int u = t + (uu << 8);
      int px = u & 63, oct = u >> 6;
      half8 h;
#pragma unroll
      for (int i = 0; i < 8; ++i) h[i] = (_Float16)tile[oct * 8 + i][px];
      *(half8*)(o + px * CIN + oct * 8) = h;
    }
  }
}

// ---------------------------------------------------------------------------
// Conv 3x3 (replicate pad) + bias + ReLU, 32x32x16 fp16 MFMA.
//
// 8-wave / 512-thread blocks (this round): same 128px x 256ch tile, but
// 2 m-waves x 4 n-waves of 64px x 64ch each -> acc 64 regs/wave, total
// ~120 VGPR -> __launch_bounds__(512,4) -> 4 waves/SIMD (2 blocks/CU),
// doubling TLP. r0-r3 showed the pipes (MFMA 33%, LDS ~43%, VALU 18%)
// run serially at 2 waves/SIMD; schedule-only fixes were null (r2) or
// negative (r3 sched_barrier - reverted). Wave-level overlap is the
// mechanism that composes them (m114).
//
// Sync skeleton (r2): each tap = ph0 {read ks1 frags, MFMA ks0} ->
// mid-tap s_waitcnt vmcnt(N) lgkmcnt(0) + barrier -> ph1 {DMA B[t+3]
// into buf t%3 (+A[cc+1] at t==6, waves 0-3), read ks0 frags of tap
// t+1, MFMA ks1}. B triple-buffered (2 dma16/wave/tile), A dbuf.
// vmcnt: prologue 4; mid-tap 2 (uniform; keeps newest B-tile flying,
// forces A ~1.2 taps after issue - covered by flight time); 0 only in
// last-cc drain (t==7,8).
// Epilogue: stage C-tile in LDS [px][264] fp16, coalesced stores.
// grid 512*NB x 512 threads; b = blockIdx>>9.
// ---------------------------------------------------------------------------
template <int CI>
__global__ __launch_bounds__(512, 4) void k_conv(
    const _Float16* __restrict__ actin, const char* __restrict__ wr,
    const float* __restrict__ bias, _Float16* __restrict__ actout) {
  constexpr int NC = CI / 32;
  constexpr int NT = 9 * NC;
  __shared__ __align__(16) char smem[73728];   // As(2x12288)+Bs(3x16384) | Qs
  auto As = (char(*)[12288])smem;
  _Float16* Qs = (_Float16*)smem;              // [128][264] fp16 (epilogue)

  int tid = threadIdx.x;
  int b = blockIdx.x >> 9;
  int tile = blockIdx.x & 511;
  int txi = tile & 15, tyi = tile >> 4;
  int x0 = txi << 4, y0 = tyi << 3;
  int lane = tid & 63, wave = tid >> 6;        // wave in 0..7
  int mwave = wave >> 2, nwave = wave & 3;     // 2m x 4n
  int l31 = lane & 31, khalf = lane >> 5;

  f32x16 acc[2][2];
#pragma unroll
  for (int s = 0; s < 2; ++s)
#pragma unroll
    for (int nt = 0; nt < 2; ++nt)
#pragma unroll
      for (int r = 0; r < 16; ++r) acc[s][nt][r] = 0.f;

  // A staging: 12 groups of 16 px, waves 0..3 handle 3 each.
  const char* aG[3];
  int aL[3];
#pragma unroll
  for (int i = 0; i < 3; ++i) {
    int px = (wave * 3 + i) * 16 + (lane >> 2);
    int s = lane & 3;
    int pxc = min(px, 179);
    int hy = pxc / 18, hx = pxc - hy * 18;
    int y = min(max(y0 - 1 + hy, 0), 255);
    int x = min(max(x0 - 1 + hx, 0), 255);
    int q = s ^ ((pxc >> 1) & 3);
    aG[i] = (const char*)actin +
            (((size_t)(b * 65536 + y * 256 + x)) * CI + q * 8) * 2;
    aL[i] = (wave * 3 + i) * 1024;
  }
  // B staging: 16KB/tile, 8 waves x 2 dma16 (1KB each).
  const char* bG = wr + wave * 2048 + lane * 16;
  int bL = wave * 2048;

  // B fragment byte offsets (ks0); ks1 = bo ^ 32.
  int bo[2];
#pragma unroll
  for (int nt = 0; nt < 2; ++nt) {
    int n = nwave * 64 + nt * 32 + l31;
    bo[nt] = n * 64 + ((khalf << 4) ^ (((n >> 1) & 3) << 4));
  }
  int pxA = (mwave * 4 + (l31 >> 4)) * 18 + (l31 & 15);

  // -------- prologue: A(cc=0) + B tiles 0,1,2; retire A,B0; keep B1,B2.
  if (wave < 4) {
#pragma unroll
    for (int i = 0; i < 3; ++i) dma16(aG[i], &As[0][aL[i]]);
  }
#pragma unroll
  for (int bufi = 0; bufi < 3; ++bufi)
#pragma unroll
    for (int i = 0; i < 2; ++i)
      dma16(bG + bufi * 16384 + i * 1024,
            smem + 24576 + bufi * 16384 + bL + i * 1024);
  asm volatile("s_waitcnt vmcnt(4)" ::: "memory");
  __builtin_amdgcn_s_barrier();

  half8 af0[2], af1[2], bf0[2], bf1[2];
  {  // pre-read set0 (ks0 of tap 0)
    const char* Ab = As[0];
    const char* Bb = smem + 24576;
#pragma unroll
    for (int s = 0; s < 2; ++s) {
      int px = pxA + s * 36;
      int a = px * 64 + ((khalf << 4) ^ (((px >> 1) & 3) << 4));
      af0[s] = *(const half8*)(Ab + a);
    }
#pragma unroll
    for (int nt = 0; nt < 2; ++nt) bf0[nt] = *(const half8*)(Bb + bo[nt]);
  }

  for (int cc = 0; cc < NC; ++cc) {
    const char* Ab = As[cc & 1];
    const char* Abn = As[(cc + 1) & 1];
    bool more = (cc + 1 < NC);
#pragma unroll
    for (int t = 0; t < 9; ++t) {
      int j = cc * 9 + t;
      const char* Bb = smem + 24576 + (t % 3) * 16384;
      const char* Bbn = smem + 24576 + ((t + 1) % 3) * 16384;
      int D = (t / 3) * 18 + (t % 3);
      // ---- ph0: read set1 (ks1, tap t), MFMA set0 (ks0) ----
#pragma unroll
      for (int s = 0; s < 2; ++s) {
        int px = pxA + s * 36 + D;
        int a = px * 64 + (((2 + khalf) << 4) ^ (((px >> 1) & 3) << 4));
        af1[s] = *(const half8*)(Ab + a);
      }
#pragma unroll
      for (int nt = 0; nt < 2; ++nt)
        bf1[nt] = *(const half8*)(Bb + (bo[nt] ^ 32));
      __builtin_amdgcn_s_setprio(1);
#pragma unroll
      for (int s = 0; s < 2; ++s)
#pragma unroll
        for (int nt = 0; nt < 2; ++nt)
          acc[s][nt] = __builtin_amdgcn_mfma_f32_32x32x16_f16(
              af0[s], bf0[nt], acc[s][nt], 0, 0, 0);
      __builtin_amdgcn_s_setprio(0);
      // ---- mid-tap sync: retire B[t+1] (read next in ph1); WAR guard
      //      (lgkmcnt(0)+barrier) for ph1's DMA into buf t%3 ----
      if (t <= 6 || more)
        asm volatile("s_waitcnt vmcnt(2) lgkmcnt(0)" ::: "memory");
      else
        asm volatile("s_waitcnt vmcnt(0) lgkmcnt(0)" ::: "memory");
      __builtin_amdgcn_s_barrier();
      // ---- ph1: DMA (A at t==6, waves 0-3; B[t+3] into buf t%3),
      //      read set0 (ks0 of tap t+1), MFMA set1 (ks1) ----
      if (t == 6 && more && wave < 4) {
#pragma unroll
        for (int i = 0; i < 3; ++i)
          dma16(aG[i] + (cc + 1) * 64, &As[(cc + 1) & 1][aL[i]]);
      }
      if (t < 6 || more) {   // j+3 < NT
        const char* bsrc = bG + (size_t)(j + 3) * 16384;
        char* bdst = smem + 24576 + (t % 3) * 16384 + bL;
#pragma unroll
        for (int i = 0; i < 2; ++i) dma16(bsrc + i * 1024, bdst + i * 1024);
      }
      if (t < 8 || more) {   // j+1 < NT
        const char* An = (t < 8) ? Ab : Abn;
        int Dn = (t < 8) ? (((t + 1) / 3) * 18 + ((t + 1) % 3)) : 0;
#pragma unroll
        for (int s = 0; s < 2; ++s) {
          int px = pxA + s * 36 + Dn;
          int a = px * 64 + ((khalf << 4) ^ (((px >> 1) & 3) << 4));
          af0[s] = *(const half8*)(An + a);
        }
#pragma unroll
        for (int nt = 0; nt < 2; ++nt)
          bf0[nt] = *(const half8*)(Bbn + bo[nt]);
      }
      __builtin_amdgcn_s_setprio(1);
#pragma unroll
      for (int s = 0; s < 2; ++s)
#pragma unroll
        for (int nt = 0; nt < 2; ++nt)
          acc[s][nt] = __builtin_amdgcn_mfma_f32_32x32x16_f16(
              af1[s], bf1[nt], acc[s][nt], 0, 0, 0);
      __builtin_amdgcn_s_setprio(0);
      // no tap-end sync: buffers touched next tap are guarded by that
      // tap's mid-tap barrier.
    }
  }
  __syncthreads();   // WAR: epilogue Qs overlays As/Bs

  // ---- epilogue: bias+relu, stage to LDS [px][264], coalesced stores ----
  // C/D: col = lane&31, row = (r&3) + 8*(r>>2) + 4*(lane>>5)
#pragma unroll
  for (int s = 0; s < 2; ++s)
#pragma unroll
    for (int nt = 0; nt < 2; ++nt) {
      int n = nwave * 64 + nt * 32 + l31;
      float bn = bias[n];
#pragma unroll
      for (int r = 0; r < 16; ++r) {
        int mrow = (r & 3) + 8 * (r >> 2) + 4 * khalf;
        int p = (mwave * 4 + s * 2 + (mrow >> 4)) * 16 + (mrow & 15);
        Qs[p * 264 + n] = (_Float16)fmaxf(acc[s][nt][r] + bn, 0.f);
      }
    }
  __syncthreads();
  {
    _Float16* gout = actout + (((size_t)(b * 65536 + y0 * 256 + x0)) << 8);
#pragma unroll
    for (int i = 0; i < 8; ++i) {
      int f = tid + (i << 9);
      int p = f >> 5, o = f & 31;
      half8 v = *(const half8*)&Qs[p * 264 + o * 8];
      *(half8*)(gout + (((p >> 4) * 256 + (p & 15)) << 8) + o * 8) = v;
    }
  }
}

// ---------------------------------------------------------------------------
// Head, all 4 batches in one dispatch. One px per thread, all fp32 VALU;
// wmu2/lgb/label wave-uniform -> scalar loads. grid 1024.
// ---------------------------------------------------------------------------
__global__ __launch_bounds__(256) void k_head(
    const _Float16* __restrict__ a2_0, const _Float16* __restrict__ a2_1,
    const _Float16* __restrict__ a2_2, const _Float16* __restrict__ a2_3,
    const float* __restrict__ wmu2, const float* __restrict__ lgb,
    const float* __restrict__ label, float* __restrict__ out) {
  int b = blockIdx.x >> 8;
  int px = (blockIdx.x & 255) * 256 + threadIdx.x;
  const _Float16* base = (b == 0) ? a2_0 : (b == 1) ? a2_1
                       : (b == 2) ? a2_2 : a2_3;
  const half8* ap = (const half8*)(base + ((size_t)px << 8));
  float cr[16];
#pragma unroll
  for (int k = 0; k < 16; ++k) cr[k] = lgb[k];
#pragma unroll 2
  for (int cc = 0; cc < 32; ++cc) {
    half8 h = ap[cc];
    float a0 = (float)h[0], a1 = (float)h[1], a2 = (float)h[2],
          a3 = (float)h[3], a4 = (float)h[4], a5 = (float)h[5],
          a6 = (float)h[6], a7 = (float)h[7];
#pragma unroll
    for (int k = 0; k < 16; ++k) {
      const float* w = wmu2 + (k << 8) + (cc << 3);
      float c0 = cr[k];
      c0 = fmaf(a0, w[0], c0);
      c0 = fmaf(a1, w[1], c0);
      c0 = fmaf(a2, w[2], c0);
      c0 = fmaf(a3, w[3], c0);
      c0 = fmaf(a4, w[4], c0);
      c0 = fmaf(a5, w[5], c0);
      c0 = fmaf(a6, w[6], c0);
      c0 = fmaf(a7, w[7], c0);
      cr[k] = c0;
    }
  }
  float mx = cr[0];
#pragma unroll
  for (int k = 1; k < 16; ++k) mx = fmaxf(mx, cr[k]);
  float num = 0.f, den = 0.f;
#pragma unroll
  for (int k = 0; k < 16; ++k) {
    float e = __expf(cr[k] - mx);
    num = fmaf(e, label[k], num);
    den += e;
  }
  out[(size_t)b * 65536 + px] = num / den;
}

// ---------------------------------------------------------------------------
extern "C" void kernel_launch(void* const* d_in, const int* in_sizes, int n_in,
                              void* d_out, int out_size, void* d_ws, size_t ws_size,
                              hipStream_t stream) {
  const float* x  = (const float*)d_in[0];
  const float* w1 = (const float*)d_in[1];
  const float* b1 = (const float*)d_in[2];
  const float* w2 = (const float*)d_in[3];
  const float* b2 = (const float*)d_in[4];
  const float* w3 = (const float*)d_in[5];
  const float* b3 = (const float*)d_in[6];
  const float* mu = (const float*)d_in[7];
  const float* label = (const float*)d_in[8];
  float* out = (float*)d_out;

  char* ws = (char*)d_ws;
  _Float16* w1r  = (_Float16*)(ws + OFF_W1R);
  _Float16* w2r  = (_Float16*)(ws + OFF_W2R);
  float*    wmu2 = (float*)   (ws + OFF_WMU);
  float*    lgb  = (float*)   (ws + OFF_LGB);
  _Float16* act0 = (_Float16*)(ws + OFF_ACT0);   // [4][HW][64], 32 MB
  _Float16* act1 = (_Float16*)(ws + OFF_ACT1);   // [4][HW][256], 128 MB
  float*    wpart = (float*)  (ws + OFF_ACT1);   // 131 KB, dead before conv1

  _Float16* a2d[4] = {
    (_Float16*)(ws + OFF_ACT0),
    act1 + 0 * (size_t)65536 * 256,
    act1 + 1 * (size_t)65536 * 256,
    act1 + 2 * (size_t)65536 * 256
  };

  k_prep<<<3024, 256, 0, stream>>>(w1, w2, w3, b3, mu, w1r, w2r, wpart, lgb);
  k_prep2<<<16, 256, 0, stream>>>(wpart, wmu2);
  k_t0<<<4096, 256, 0, stream>>>(x, act0);
  k_conv<64><<<2048, 512, 0, stream>>>(act0, (const char*)w1r, b1, act1);
  for (int b = 0; b < BB; ++b)
    k_conv<256><<<512, 512, 0, stream>>>(act1 + (size_t)b * 65536 * 256,
                                         (const char*)w2r, b2, a2d[b]);
  k_head<<<1024, 256, 0, stream>>>(a2d[0], a2d[1], a2d[2], a2d[3],
                                   wmu2, lgb, label, out);
}

// Round 6
// 694.217 us; speedup vs baseline: 1.3873x; 1.3873x over previous
//
#include <hip/hip_runtime.h>

// Problem constants
#define BB   4
#define CIN  64
#define HH   256
#define WW   256
#define QQ   256
#define KK   16

typedef _Float16 half8 __attribute__((ext_vector_type(8)));
typedef float   f32x16 __attribute__((ext_vector_type(16)));
typedef unsigned int u32;

// ---- workspace layout (bytes); r8 proved ws_size >= 169378048 ----
#define OFF_W1R   0ull
#define OFF_W2R   294912ull
#define OFF_WMU   1474560ull
#define OFF_LGB   1490944ull
#define OFF_ACT0  1605888ull
#define OFF_ACT1  35160320ull

__device__ __forceinline__ void dma16(const void* g, void* l) {
  __builtin_amdgcn_global_load_lds(
      (const __attribute__((address_space(1))) u32*)g,
      (__attribute__((address_space(3))) u32*)l, 16, 0, 0);
}

// ---------------------------------------------------------------------------
// Prep. Blocks 0..575: w1r; 576..2879: w2r; 2880..3007: wmu2 partials;
// 3008..3023: lgb. Weight image block (cc,tt)=16KB: 256 rows x 32ch;
// 16B-quarter q of row n stored at slot q^((n>>1)&3).
// ---------------------------------------------------------------------------
__global__ __launch_bounds__(256) void k_prep(
    const float* __restrict__ w1, const float* __restrict__ w2,
    const float* __restrict__ w3, const float* __restrict__ b3,
    const float* __restrict__ mu,
    _Float16* __restrict__ w1r, _Float16* __restrict__ w2r,
    float* __restrict__ wpart, float* __restrict__ lgb) {
  int bid = blockIdx.x, tid = threadIdx.x;
  if (bid < 576) {                          // w1r (CI=64)
    int idx = bid * 256 + tid;
    int blk = idx >> 13;
    int cc = blk / 9, tt = blk - cc * 9;
    int rem = idx & 8191;
    int n = rem >> 5, r = rem & 31;
    int q = (r >> 3) ^ ((n >> 1) & 3), e = r & 7;
    int c = cc * 32 + q * 8 + e;
    w1r[idx] = (_Float16)w1[(n * 64 + c) * 9 + tt];
  } else if (bid < 2880) {                  // w2r (CI=256)
    int d = (bid - 576) * 256 + tid;
    int blk = d >> 13;
    int cc = blk / 9, tt = blk - cc * 9;
    int rem = d & 8191;
    int n = rem >> 5, r = rem & 31;
    int q = (r >> 3) ^ ((n >> 1) & 3), e = r & 7;
    int c = cc * 32 + q * 8 + e;
    w2r[d] = (_Float16)w2[(n * 256 + c) * 9 + tt];
  } else if (bid < 3008) {                  // wmu2 partials
    int j = bid - 2880;
    int k = j >> 3, o0 = (j & 7) << 5;
    float s = 0.f;
#pragma unroll 4
    for (int oi = 0; oi < 32; ++oi) {
      int o = o0 + oi;
      s = fmaf(mu[k * 256 + o], w3[o * 256 + tid], s);
    }
    wpart[j * 256 + tid] = s;
  } else {                                  // lgb, one block per k
    int k = bid - 3008;
    float m = mu[k * 256 + tid];
    __shared__ float red[256];
    red[tid] = m * (2.f * b3[tid] - m);
    __syncthreads();
    for (int st = 128; st > 0; st >>= 1) {
      if (tid < st) red[tid] += red[tid + st];
      __syncthreads();
    }
    if (tid == 0) lgb[k] = red[0];
  }
}

// Reduce wmu2 partials: wmu2[k][c] = 2 * sum_p wpart[k*8+p][c]. 16 blocks.
__global__ __launch_bounds__(256) void k_prep2(
    const float* __restrict__ wpart, float* __restrict__ wmu2) {
  int k = blockIdx.x, tid = threadIdx.x;
  float s = 0.f;
#pragma unroll
  for (int p = 0; p < 8; ++p) s += wpart[(k * 8 + p) * 256 + tid];
  wmu2[k * 256 + tid] = 2.f * s;
}

// ---------------------------------------------------------------------------
// T0: x NCHW fp32 -> act0 [b][HW][64] fp16, all 4 batches. grid 4096.
// ---------------------------------------------------------------------------
__global__ __launch_bounds__(256) void k_t0(const float* __restrict__ x,
                                            _Float16* __restrict__ act0) {
  __shared__ float tile[64][65];
  int blk = blockIdx.x;
  int b = blk >> 10;
  int p0 = (blk & 1023) << 6;
  int t = threadIdx.x;
  {
    int p = t & 63, c0 = t >> 6;
    const float* xb = x + (size_t)b * (CIN * 65536) + p0 + p;
#pragma unroll
    for (int i = 0; i < 16; ++i) {
      int c = c0 + (i << 2);
      tile[c][p] = xb[(size_t)c * 65536];
    }
  }
  __syncthreads();
  {
    _Float16* o = act0 + (size_t)(b * 65536 + p0) * CIN;
#pragma unroll
    for (int uu = 0; uu < 2; ++uu) {
      int u = t + (uu << 8);
      int px = u & 63, oct = u >> 6;
      half8 h;
#pragma unroll
      for (int i = 0; i < 8; ++i) h[i] = (_Float16)tile[oct * 8 + i][px];
      *(half8*)(o + px * CIN + oct * 8) = h;
    }
  }
}

// ---------------------------------------------------------------------------
// Conv 3x3 (replicate pad) + bias + ReLU, 32x32x16 fp16 MFMA.
//
// 8-wave / 512-thread / REGISTER-LEAN (unchanged from r4-proposal; r5
// bench never ran - GPU acquisition timeout). r4 proved the 8-wave
// occupancy mechanism (41% occ) but spilled: launch_bounds(512,4) caps
// 128 unified regs/wave and the cross-phase prefetch state didn't fit
// (VGPR 64 + scratch: FETCH 23->115 MB). This version fits: acc 64
// (2x2 32x32 frags, 64px x 64ch per wave) + 4 JIT fragments (16 VGPR,
// reused across K-halves) + lean addressing (~25) ~= 105 < 128. No
// intra-wave pipelining at all - at 4 waves/SIMD, TLP hides LDS/MFMA
// latency (m114); r2/r3 showed intra-wave scheduling is not the lever.
//
// Per tap: [t==8: A(cc+1) DMA first, waves 0-3] -> B[t+2] DMA (2/wave,
// buf (t+2)%3) -> JIT ds_read ks0 frags -> 4 MFMA -> JIT ks1 -> 4 MFMA
// -> s_waitcnt vmcnt(N) lgkmcnt(0) + barrier. Steady state outstanding
// at tap end = B[t+1](2)+B[t+2](2) -> vmcnt(2) retires B[t+1], keeps
// B[t+2] flying. t==8: A(3) issued before B -> queue B[t+1],A,B[t+2] ->
// vmcnt(2) retires B[t+1]+A. Drain (last cc): t==7 has no new issue ->
// vmcnt(0) retires B[last]; t==8 trivial. lgkmcnt(0)+barrier = WAR guard
// for next tap's DMA into buf (t+3)%3 == t%3.
// Epilogue: stage C-tile in LDS [px][264] fp16, coalesced stores.
// grid 512*NB x 512 threads; b = blockIdx>>9.
// ---------------------------------------------------------------------------
template <int CI>
__global__ __launch_bounds__(512, 4) void k_conv(
    const _Float16* __restrict__ actin, const char* __restrict__ wr,
    const float* __restrict__ bias, _Float16* __restrict__ actout) {
  constexpr int NC = CI / 32;
  constexpr int NT = 9 * NC;
  __shared__ __align__(16) char smem[73728];   // As(2x12288)+Bs(3x16384) | Qs
  auto As = (char(*)[12288])smem;
  _Float16* Qs = (_Float16*)smem;              // [128][264] fp16 (epilogue)

  int tid = threadIdx.x;
  int b = blockIdx.x >> 9;
  int tile = blockIdx.x & 511;
  int txi = tile & 15, tyi = tile >> 4;
  int x0 = txi << 4, y0 = tyi << 3;
  int lane = tid & 63, wave = tid >> 6;        // wave in 0..7
  int mwave = wave >> 2, nwave = wave & 3;     // 2m x 4n
  int l31 = lane & 31, khalf = lane >> 5;

  f32x16 acc00, acc01, acc10, acc11;
#pragma unroll
  for (int r = 0; r < 16; ++r) {
    acc00[r] = 0.f; acc01[r] = 0.f; acc10[r] = 0.f; acc11[r] = 0.f;
  }

  // A staging: 12 groups of 16 px, waves 0..3 handle 3 each.
  const char* aG[3];
  int aL[3];
  if (wave < 4) {
#pragma unroll
    for (int i = 0; i < 3; ++i) {
      int px = (wave * 3 + i) * 16 + (lane >> 2);
      int s = lane & 3;
      int pxc = min(px, 179);
      int hy = pxc / 18, hx = pxc - hy * 18;
      int y = min(max(y0 - 1 + hy, 0), 255);
      int x = min(max(x0 - 1 + hx, 0), 255);
      int q = s ^ ((pxc >> 1) & 3);
      aG[i] = (const char*)actin +
              (((size_t)(b * 65536 + y * 256 + x)) * CI + q * 8) * 2;
      aL[i] = (wave * 3 + i) * 1024;
    }
  }
  // B staging: 16KB/tile, 8 waves x 2 dma16 (1KB each).
  const char* bG = wr + wave * 2048 + lane * 16;
  int bL = wave * 2048;

  // B fragment byte offsets (ks0); ks1 = bo ^ 32.
  int bo0, bo1;
  {
    int n0 = nwave * 64 + l31;
    int n1 = n0 + 32;
    bo0 = n0 * 64 + ((khalf << 4) ^ (((n0 >> 1) & 3) << 4));
    bo1 = n1 * 64 + ((khalf << 4) ^ (((n1 >> 1) & 3) << 4));
  }
  int pxA = (mwave * 4 + (l31 >> 4)) * 18 + (l31 & 15);

  // -------- prologue: A(cc=0) + B tiles 0,1; retire A,B0; keep B1.
  if (wave < 4) {
#pragma unroll
    for (int i = 0; i < 3; ++i) dma16(aG[i], &As[0][aL[i]]);
  }
#pragma unroll
  for (int bufi = 0; bufi < 2; ++bufi)
#pragma unroll
    for (int i = 0; i < 2; ++i)
      dma16(bG + bufi * 16384 + i * 1024,
            smem + 24576 + bufi * 16384 + bL + i * 1024);
  asm volatile("s_waitcnt vmcnt(2)" ::: "memory");
  __builtin_amdgcn_s_barrier();

  for (int cc = 0; cc < NC; ++cc) {
    const char* Ab = As[cc & 1];
    bool more = (cc + 1 < NC);
#pragma unroll
    for (int t = 0; t < 9; ++t) {
      int j = cc * 9 + t;
      bool pf = (j + 2 < NT);
      // ---- DMA issue: A (t==8, waves 0-3, FIRST) then B[t+2] ----
      if (t == 8 && more && wave < 4) {
#pragma unroll
        for (int i = 0; i < 3; ++i)
          dma16(aG[i] + (cc + 1) * 64, &As[(cc + 1) & 1][aL[i]]);
      }
      if (pf) {
        const char* bsrc = bG + (size_t)(j + 2) * 16384;
        char* bdst = smem + 24576 + ((t + 2) % 3) * 16384 + bL;
#pragma unroll
        for (int i = 0; i < 2; ++i) dma16(bsrc + i * 1024, bdst + i * 1024);
      }
      // ---- compute: JIT fragment reads, 8 MFMA ----
      const char* Bb = smem + 24576 + (t % 3) * 16384;
      int D = (t / 3) * 18 + (t % 3);
      int px0 = pxA + D, px1 = pxA + 36 + D;
      int sw0 = ((px0 >> 1) & 3) << 4, sw1 = ((px1 >> 1) & 3) << 4;
      half8 a0, a1, bf0, bf1;
      // ks0
      a0 = *(const half8*)(Ab + px0 * 64 + ((khalf << 4) ^ sw0));
      a1 = *(const half8*)(Ab + px1 * 64 + ((khalf << 4) ^ sw1));
      bf0 = *(const half8*)(Bb + bo0);
      bf1 = *(const half8*)(Bb + bo1);
      __builtin_amdgcn_s_setprio(1);
      acc00 = __builtin_amdgcn_mfma_f32_32x32x16_f16(a0, bf0, acc00, 0, 0, 0);
      acc01 = __builtin_amdgcn_mfma_f32_32x32x16_f16(a0, bf1, acc01, 0, 0, 0);
      acc10 = __builtin_amdgcn_mfma_f32_32x32x16_f16(a1, bf0, acc10, 0, 0, 0);
      acc11 = __builtin_amdgcn_mfma_f32_32x32x16_f16(a1, bf1, acc11, 0, 0, 0);
      __builtin_amdgcn_s_setprio(0);
      // ks1
      a0 = *(const half8*)(Ab + px0 * 64 + (((2 + khalf) << 4) ^ sw0));
      a1 = *(const half8*)(Ab + px1 * 64 + (((2 + khalf) << 4) ^ sw1));
      bf0 = *(const half8*)(Bb + (bo0 ^ 32));
      bf1 = *(const half8*)(Bb + (bo1 ^ 32));
      __builtin_amdgcn_s_setprio(1);
      acc00 = __builtin_amdgcn_mfma_f32_32x32x16_f16(a0, bf0, acc00, 0, 0, 0);
      acc01 = __builtin_amdgcn_mfma_f32_32x32x16_f16(a0, bf1, acc01, 0, 0, 0);
      acc10 = __builtin_amdgcn_mfma_f32_32x32x16_f16(a1, bf0, acc10, 0, 0, 0);
      acc11 = __builtin_amdgcn_mfma_f32_32x32x16_f16(a1, bf1, acc11, 0, 0, 0);
      __builtin_amdgcn_s_setprio(0);
      // ---- tap-end sync: retire B[t+1] (+A at t==8); keep B[t+2].
      //      lgkmcnt(0)+barrier = WAR guard for next tap's DMA ----
      if (pf)
        asm volatile("s_waitcnt vmcnt(2) lgkmcnt(0)" ::: "memory");
      else
        asm volatile("s_waitcnt vmcnt(0) lgkmcnt(0)" ::: "memory");
      __builtin_amdgcn_s_barrier();
    }
  }

  // ---- epilogue: bias+relu, stage to LDS [px][264], coalesced stores ----
  // C/D: col = lane&31, row = (r&3) + 8*(r>>2) + 4*(lane>>5)
#pragma unroll
  for (int s = 0; s < 2; ++s)
#pragma unroll
    for (int nt = 0; nt < 2; ++nt) {
      int n = nwave * 64 + nt * 32 + l31;
      float bn = bias[n];
      const f32x16& a = (s == 0) ? (nt == 0 ? acc00 : acc01)
                                 : (nt == 0 ? acc10 : acc11);
#pragma unroll
      for (int r = 0; r < 16; ++r) {
        int mrow = (r & 3) + 8 * (r >> 2) + 4 * khalf;
        int p = (mwave * 4 + s * 2 + (mrow >> 4)) * 16 + (mrow & 15);
        Qs[p * 264 + n] = (_Float16)fmaxf(a[r] + bn, 0.f);
      }
    }
  __syncthreads();
  {
    _Float16* gout = actout + (((size_t)(b * 65536 + y0 * 256 + x0)) << 8);
#pragma unroll
    for (int i = 0; i < 8; ++i) {
      int f = tid + (i << 9);
      int p = f >> 5, o = f & 31;
      half8 v = *(const half8*)&Qs[p * 264 + o * 8];
      *(half8*)(gout + (((p >> 4) * 256 + (p & 15)) << 8) + o * 8) = v;
    }
  }
}

// ---------------------------------------------------------------------------
// Head, all 4 batches in one dispatch. One px per thread, all fp32 VALU;
// wmu2/lgb/label wave-uniform -> scalar loads. grid 1024.
// ---------------------------------------------------------------------------
__global__ __launch_bounds__(256) void k_head(
    const _Float16* __restrict__ a2_0, const _Float16* __restrict__ a2_1,
    const _Float16* __restrict__ a2_2, const _Float16* __restrict__ a2_3,
    const float* __restrict__ wmu2, const float* __restrict__ lgb,
    const float* __restrict__ label, float* __restrict__ out) {
  int b = blockIdx.x >> 8;
  int px = (blockIdx.x & 255) * 256 + threadIdx.x;
  const _Float16* base = (b == 0) ? a2_0 : (b == 1) ? a2_1
                       : (b == 2) ? a2_2 : a2_3;
  const half8* ap = (const half8*)(base + ((size_t)px << 8));
  float cr[16];
#pragma unroll
  for (int k = 0; k < 16; ++k) cr[k] = lgb[k];
#pragma unroll 2
  for (int cc = 0; cc < 32; ++cc) {
    half8 h = ap[cc];
    float a0 = (float)h[0], a1 = (float)h[1], a2 = (float)h[2],
          a3 = (float)h[3], a4 = (float)h[4], a5 = (float)h[5],
          a6 = (float)h[6], a7 = (float)h[7];
#pragma unroll
    for (int k = 0; k < 16; ++k) {
      const float* w = wmu2 + (k << 8) + (cc << 3);
      float c0 = cr[k];
      c0 = fmaf(a0, w[0], c0);
      c0 = fmaf(a1, w[1], c0);
      c0 = fmaf(a2, w[2], c0);
      c0 = fmaf(a3, w[3], c0);
      c0 = fmaf(a4, w[4], c0);
      c0 = fmaf(a5, w[5], c0);
      c0 = fmaf(a6, w[6], c0);
      c0 = fmaf(a7, w[7], c0);
      cr[k] = c0;
    }
  }
  float mx = cr[0];
#pragma unroll
  for (int k = 1; k < 16; ++k) mx = fmaxf(mx, cr[k]);
  float num = 0.f, den = 0.f;
#pragma unroll
  for (int k = 0; k < 16; ++k) {
    float e = __expf(cr[k] - mx);
    num = fmaf(e, label[k], num);
    den += e;
  }
  out[(size_t)b * 65536 + px] = num / den;
}

// ---------------------------------------------------------------------------
extern "C" void kernel_launch(void* const* d_in, const int* in_sizes, int n_in,
                              void* d_out, int out_size, void* d_ws, size_t ws_size,
                              hipStream_t stream) {
  const float* x  = (const float*)d_in[0];
  const float* w1 = (const float*)d_in[1];
  const float* b1 = (const float*)d_in[2];
  const float* w2 = (const float*)d_in[3];
  const float* b2 = (const float*)d_in[4];
  const float* w3 = (const float*)d_in[5];
  const float* b3 = (const float*)d_in[6];
  const float* mu = (const float*)d_in[7];
  const float* label = (const float*)d_in[8];
  float* out = (float*)d_out;

  char* ws = (char*)d_ws;
  _Float16* w1r  = (_Float16*)(ws + OFF_W1R);
  _Float16* w2r  = (_Float16*)(ws + OFF_W2R);
  float*    wmu2 = (float*)   (ws + OFF_WMU);
  float*    lgb  = (float*)   (ws + OFF_LGB);
  _Float16* act0 = (_Float16*)(ws + OFF_ACT0);   // [4][HW][64], 32 MB
  _Float16* act1 = (_Float16*)(ws + OFF_ACT1);   // [4][HW][256], 128 MB
  float*    wpart = (float*)  (ws + OFF_ACT1);   // 131 KB, dead before conv1

  _Float16* a2d[4] = {
    (_Float16*)(ws + OFF_ACT0),
    act1 + 0 * (size_t)65536 * 256,
    act1 + 1 * (size_t)65536 * 256,
    act1 + 2 * (size_t)65536 * 256
  };

  k_prep<<<3024, 256, 0, stream>>>(w1, w2, w3, b3, mu, w1r, w2r, wpart, lgb);
  k_prep2<<<16, 256, 0, stream>>>(wpart, wmu2);
  k_t0<<<4096, 256, 0, stream>>>(x, act0);
  k_conv<64><<<2048, 512, 0, stream>>>(act0, (const char*)w1r, b1, act1);
  for (int b = 0; b < BB; ++b)
    k_conv<256><<<512, 512, 0, stream>>>(act1 + (size_t)b * 65536 * 256,
                                         (const char*)w2r, b2, a2d[b]);
  k_head<<<1024, 256, 0, stream>>>(a2d[0], a2d[1], a2d[2], a2d[3],
                                   wmu2, lgb, label, out);
}

// Round 7
// 617.087 us; speedup vs baseline: 1.5607x; 1.1250x over previous
//
#include <hip/hip_runtime.h>

// Problem constants
#define BB   4
#define CIN  64
#define HH   256
#define WW   256
#define QQ   256
#define KK   16

typedef _Float16 half8 __attribute__((ext_vector_type(8)));
typedef float   f32x16 __attribute__((ext_vector_type(16)));
typedef unsigned int u32;

// ---- workspace layout (bytes); r8 proved ws_size >= 169378048 ----
#define OFF_W1R   0ull
#define OFF_W2R   294912ull
#define OFF_WMU   1474560ull
#define OFF_LGB   1490944ull
#define OFF_ACT0  1605888ull
#define OFF_ACT1  35160320ull

__device__ __forceinline__ void dma16(const void* g, void* l) {
  __builtin_amdgcn_global_load_lds(
      (const __attribute__((address_space(1))) u32*)g,
      (__attribute__((address_space(3))) u32*)l, 16, 0, 0);
}

// ---------------------------------------------------------------------------
// Prep. Blocks 0..575: w1r; 576..2879: w2r; 2880..3007: wmu2 partials;
// 3008..3023: lgb. Weight image block (cc,tt)=16KB: 256 rows x 32ch;
// 16B-quarter q of row n stored at slot q^((n>>1)&3).
// ---------------------------------------------------------------------------
__global__ __launch_bounds__(256) void k_prep(
    const float* __restrict__ w1, const float* __restrict__ w2,
    const float* __restrict__ w3, const float* __restrict__ b3,
    const float* __restrict__ mu,
    _Float16* __restrict__ w1r, _Float16* __restrict__ w2r,
    float* __restrict__ wpart, float* __restrict__ lgb) {
  int bid = blockIdx.x, tid = threadIdx.x;
  if (bid < 576) {                          // w1r (CI=64)
    int idx = bid * 256 + tid;
    int blk = idx >> 13;
    int cc = blk / 9, tt = blk - cc * 9;
    int rem = idx & 8191;
    int n = rem >> 5, r = rem & 31;
    int q = (r >> 3) ^ ((n >> 1) & 3), e = r & 7;
    int c = cc * 32 + q * 8 + e;
    w1r[idx] = (_Float16)w1[(n * 64 + c) * 9 + tt];
  } else if (bid < 2880) {                  // w2r (CI=256)
    int d = (bid - 576) * 256 + tid;
    int blk = d >> 13;
    int cc = blk / 9, tt = blk - cc * 9;
    int rem = d & 8191;
    int n = rem >> 5, r = rem & 31;
    int q = (r >> 3) ^ ((n >> 1) & 3), e = r & 7;
    int c = cc * 32 + q * 8 + e;
    w2r[d] = (_Float16)w2[(n * 256 + c) * 9 + tt];
  } else if (bid < 3008) {                  // wmu2 partials
    int j = bid - 2880;
    int k = j >> 3, o0 = (j & 7) << 5;
    float s = 0.f;
#pragma unroll 4
    for (int oi = 0; oi < 32; ++oi) {
      int o = o0 + oi;
      s = fmaf(mu[k * 256 + o], w3[o * 256 + tid], s);
    }
    wpart[j * 256 + tid] = s;
  } else {                                  // lgb, one block per k
    int k = bid - 3008;
    float m = mu[k * 256 + tid];
    __shared__ float red[256];
    red[tid] = m * (2.f * b3[tid] - m);
    __syncthreads();
    for (int st = 128; st > 0; st >>= 1) {
      if (tid < st) red[tid] += red[tid + st];
      __syncthreads();
    }
    if (tid == 0) lgb[k] = red[0];
  }
}

// Reduce wmu2 partials: wmu2[k][c] = 2 * sum_p wpart[k*8+p][c]. 16 blocks.
__global__ __launch_bounds__(256) void k_prep2(
    const float* __restrict__ wpart, float* __restrict__ wmu2) {
  int k = blockIdx.x, tid = threadIdx.x;
  float s = 0.f;
#pragma unroll
  for (int p = 0; p < 8; ++p) s += wpart[(k * 8 + p) * 256 + tid];
  wmu2[k * 256 + tid] = 2.f * s;
}

// ---------------------------------------------------------------------------
// T0: x NCHW fp32 -> act0 [b][HW][64] fp16, all 4 batches. grid 4096.
// ---------------------------------------------------------------------------
__global__ __launch_bounds__(256) void k_t0(const float* __restrict__ x,
                                            _Float16* __restrict__ act0) {
  __shared__ float tile[64][65];
  int blk = blockIdx.x;
  int b = blk >> 10;
  int p0 = (blk & 1023) << 6;
  int t = threadIdx.x;
  {
    int p = t & 63, c0 = t >> 6;
    const float* xb = x + (size_t)b * (CIN * 65536) + p0 + p;
#pragma unroll
    for (int i = 0; i < 16; ++i) {
      int c = c0 + (i << 2);
      tile[c][p] = xb[(size_t)c * 65536];
    }
  }
  __syncthreads();
  {
    _Float16* o = act0 + (size_t)(b * 65536 + p0) * CIN;
#pragma unroll
    for (int uu = 0; uu < 2; ++uu) {
      int u = t + (uu << 8);
      int px = u & 63, oct = u >> 6;
      half8 h;
#pragma unroll
      for (int i = 0; i < 8; ++i) h[i] = (_Float16)tile[oct * 8 + i][px];
      *(half8*)(o + px * CIN + oct * 8) = h;
    }
  }
}

// ---------------------------------------------------------------------------
// Conv 3x3 (replicate pad) + bias + ReLU, 32x32x16 fp16 MFMA, DMA staging,
// XOR-swizzled LDS (slot = q ^ ((row>>1)&3)). Block: 128 px x 256 ch,
// 256 threads = 4 waves (2m x 2n), 64 acc + frags = 2 blocks/CU.
//
// This is the session-best verified structure (r1: conv 93.2 us, total
// 588): B triple-buffered with counted vmcnt - the newest B-tile's 4
// loads stay in flight ACROSS the tap barrier (vmcnt(4)); only the
// 2-tap-old tile must have landed. lgkmcnt(0) before the barrier is the
// WAR guard for buffer reuse. A double-buffered, prefetched at t==8
// (issued FIRST so the uniform vmcnt(4) retires it). Drain vmcnt(0)
// only in the last-cc taps. s_setprio(1) wraps the MFMA cluster.
//
// Known walls (r2-r6): register cap (256/wave at 2 blk/CU) forbids a
// better MFMA:ds_read ratio (acc = 16*A*B regs) and forbids 4 waves/SIMD
// (r4/r6 spill); sched_barrier pinning regresses (r3). LDS-pipe floor
// ~74 us/dispatch; barrier convergence puts us ~26% above it.
// SQ_LDS_BANK_CONFLICT = exactly 4*b128-reads = intrinsic, not fixable.
//
// One delta vs r1: skip the duplicate DMA of B-tile 2 at cc==0,t==0
// (prologue already loaded it) - identical semantics, less L2 traffic.
// Epilogue: stage C-tile in LDS [px][264] fp16, coalesced dwordx4 stores.
// grid 512*NB; b = blockIdx>>9.
// ---------------------------------------------------------------------------
template <int CI>
__global__ __launch_bounds__(256, 2) void k_conv(
    const _Float16* __restrict__ actin, const char* __restrict__ wr,
    const float* __restrict__ bias, _Float16* __restrict__ actout) {
  constexpr int NC = CI / 32;
  constexpr int NT = 9 * NC;
  __shared__ __align__(16) char smem[73728];   // As(2x12288)+Bs(3x16384) | Qs
  auto As = (char(*)[12288])smem;
  auto Bs = (char(*)[16384])(smem + 24576);
  _Float16* Qs = (_Float16*)smem;              // [128][264] fp16 (epilogue)

  int tid = threadIdx.x;
  int b = blockIdx.x >> 9;
  int tile = blockIdx.x & 511;
  int txi = tile & 15, tyi = tile >> 4;
  int x0 = txi << 4, y0 = tyi << 3;
  int lane = tid & 63, wave = tid >> 6;
  int mwave = wave >> 1, nwave = wave & 1;
  int l31 = lane & 31, khalf = lane >> 5;

  f32x16 acc[2][4];
#pragma unroll
  for (int s = 0; s < 2; ++s)
#pragma unroll
    for (int nt = 0; nt < 4; ++nt)
#pragma unroll
      for (int r = 0; r < 16; ++r) acc[s][nt][r] = 0.f;

  const char* aG[3];
  int aL[3];
#pragma unroll
  for (int i = 0; i < 3; ++i) {
    int px = (wave * 3 + i) * 16 + (lane >> 2);
    int s = lane & 3;
    int pxc = min(px, 179);
    int hy = pxc / 18, hx = pxc - hy * 18;
    int y = min(max(y0 - 1 + hy, 0), 255);
    int x = min(max(x0 - 1 + hx, 0), 255);
    int q = s ^ ((pxc >> 1) & 3);
    aG[i] = (const char*)actin +
            (((size_t)(b * 65536 + y * 256 + x)) * CI + q * 8) * 2;
    aL[i] = (wave * 3 + i) * 1024;
  }
  const char* bG = wr + wave * 4096 + lane * 16;
  int bL = wave * 4096;

  // -------- prologue: A(cc=0), B(tap0), B(tap1), B(tap2); keep tap2 flying
#pragma unroll
  for (int i = 0; i < 3; ++i) dma16(aG[i], &As[0][aL[i]]);
#pragma unroll
  for (int i = 0; i < 4; ++i) dma16(bG + i * 1024, &Bs[0][bL + i * 1024]);
#pragma unroll
  for (int i = 0; i < 4; ++i)
    dma16(bG + 16384 + i * 1024, &Bs[1][bL + i * 1024]);
#pragma unroll
  for (int i = 0; i < 4; ++i)
    dma16(bG + 32768 + i * 1024, &Bs[2][bL + i * 1024]);
  asm volatile("s_waitcnt vmcnt(4)" ::: "memory");
  __builtin_amdgcn_s_barrier();

  for (int cc = 0; cc < NC; ++cc) {
#pragma unroll
    for (int t = 0; t < 9; ++t) {
      int j = cc * 9 + t;
      // A prefetch for next cc: issued FIRST so vmcnt(4) below retires it.
      if (t == 8 && cc + 1 < NC) {
#pragma unroll
        for (int i = 0; i < 3; ++i)
          dma16(aG[i] + (cc + 1) * 64, &As[(cc + 1) & 1][aL[i]]);
      }
      bool pf = (j + 2 < NT) && (j != 0);   // j==0: tile 2 already staged
      if (pf) {
        const char* bsrc = bG + (size_t)(j + 2) * 16384;
        char* bdst = &Bs[(t + 2) % 3][bL];
#pragma unroll
        for (int i = 0; i < 4; ++i) dma16(bsrc + i * 1024, bdst + i * 1024);
      }
      int dy = t / 3, dx = t - dy * 3;
      const char* Ab = As[cc & 1];
      const char* Bb = Bs[t % 3];
      half8 af[2][2], bf[2][4];
#pragma unroll
      for (int s = 0; s < 2; ++s) {
        int px = (mwave * 4 + s * 2 + (l31 >> 4) + dy) * 18 + (l31 & 15) + dx;
        int sw = ((px >> 1) & 3) << 4;
#pragma unroll
        for (int ks = 0; ks < 2; ++ks) {
          int q = (ks * 2 + khalf) << 4;
          af[ks][s] = *(const half8*)(Ab + px * 64 + (q ^ sw));
        }
      }
#pragma unroll
      for (int nt = 0; nt < 4; ++nt) {
        int n = nwave * 128 + nt * 32 + l31;
        int sw = ((n >> 1) & 3) << 4;
#pragma unroll
        for (int ks = 0; ks < 2; ++ks) {
          int q = (ks * 2 + khalf) << 4;
          bf[ks][nt] = *(const half8*)(Bb + n * 64 + (q ^ sw));
        }
      }
      __builtin_amdgcn_s_setprio(1);
#pragma unroll
      for (int ks = 0; ks < 2; ++ks)
#pragma unroll
        for (int s = 0; s < 2; ++s)
#pragma unroll
          for (int nt = 0; nt < 4; ++nt)
            acc[s][nt] = __builtin_amdgcn_mfma_f32_32x32x16_f16(
                af[ks][s], bf[ks][nt], acc[s][nt], 0, 0, 0);
      __builtin_amdgcn_s_setprio(0);
      // Counted wait: tap j+1 (2-tap-old loads) must be home; tap j+2's 4
      // loads stay in flight across the barrier. lgkmcnt(0) = WAR guard.
      if (j + 2 < NT)
        asm volatile("s_waitcnt vmcnt(4) lgkmcnt(0)" ::: "memory");
      else
        asm volatile("s_waitcnt vmcnt(0) lgkmcnt(0)" ::: "memory");
      __builtin_amdgcn_s_barrier();
    }
  }

  // ---- epilogue: bias+relu, stage to LDS [px][264], coalesced stores ----
  // C/D: col = lane&31, row = (r&3) + 8*(r>>2) + 4*(lane>>5)
#pragma unroll
  for (int s = 0; s < 2; ++s)
#pragma unroll
    for (int nt = 0; nt < 4; ++nt) {
      int n = nwave * 128 + nt * 32 + l31;
      float bn = bias[n];
#pragma unroll
      for (int r = 0; r < 16; ++r) {
        int mrow = (r & 3) + 8 * (r >> 2) + 4 * khalf;
        int p = (mwave * 4 + s * 2 + (mrow >> 4)) * 16 + (mrow & 15);
        Qs[p * 264 + n] = (_Float16)fmaxf(acc[s][nt][r] + bn, 0.f);
      }
    }
  __syncthreads();
  {
    _Float16* gout = actout + (((size_t)(b * 65536 + y0 * 256 + x0)) << 8);
#pragma unroll
    for (int i = 0; i < 16; ++i) {
      int f = tid + (i << 8);
      int p = f >> 5, o = f & 31;
      half8 v = *(const half8*)&Qs[p * 264 + o * 8];
      *(half8*)(gout + (((p >> 4) * 256 + (p & 15)) << 8) + o * 8) = v;
    }
  }
}

// ---------------------------------------------------------------------------
// Head, all 4 batches in one dispatch. One px per thread, all fp32 VALU;
// wmu2/lgb/label wave-uniform -> scalar loads. grid 1024.
// ---------------------------------------------------------------------------
__global__ __launch_bounds__(256) void k_head(
    const _Float16* __restrict__ a2_0, const _Float16* __restrict__ a2_1,
    const _Float16* __restrict__ a2_2, const _Float16* __restrict__ a2_3,
    const float* __restrict__ wmu2, const float* __restrict__ lgb,
    const float* __restrict__ label, float* __restrict__ out) {
  int b = blockIdx.x >> 8;
  int px = (blockIdx.x & 255) * 256 + threadIdx.x;
  const _Float16* base = (b == 0) ? a2_0 : (b == 1) ? a2_1
                       : (b == 2) ? a2_2 : a2_3;
  const half8* ap = (const half8*)(base + ((size_t)px << 8));
  float cr[16];
#pragma unroll
  for (int k = 0; k < 16; ++k) cr[k] = lgb[k];
#pragma unroll 2
  for (int cc = 0; cc < 32; ++cc) {
    half8 h = ap[cc];
    float a0 = (float)h[0], a1 = (float)h[1], a2 = (float)h[2],
          a3 = (float)h[3], a4 = (float)h[4], a5 = (float)h[5],
          a6 = (float)h[6], a7 = (float)h[7];
#pragma unroll
    for (int k = 0; k < 16; ++k) {
      const float* w = wmu2 + (k << 8) + (cc << 3);
      float c0 = cr[k];
      c0 = fmaf(a0, w[0], c0);
      c0 = fmaf(a1, w[1], c0);
      c0 = fmaf(a2, w[2], c0);
      c0 = fmaf(a3, w[3], c0);
      c0 = fmaf(a4, w[4], c0);
      c0 = fmaf(a5, w[5], c0);
      c0 = fmaf(a6, w[6], c0);
      c0 = fmaf(a7, w[7], c0);
      cr[k] = c0;
    }
  }
  float mx = cr[0];
#pragma unroll
  for (int k = 1; k < 16; ++k) mx = fmaxf(mx, cr[k]);
  float num = 0.f, den = 0.f;
#pragma unroll
  for (int k = 0; k < 16; ++k) {
    float e = __expf(cr[k] - mx);
    num = fmaf(e, label[k], num);
    den += e;
  }
  out[(size_t)b * 65536 + px] = num / den;
}

// ---------------------------------------------------------------------------
extern "C" void kernel_launch(void* const* d_in, const int* in_sizes, int n_in,
                              void* d_out, int out_size, void* d_ws, size_t ws_size,
                              hipStream_t stream) {
  const float* x  = (const float*)d_in[0];
  const float* w1 = (const float*)d_in[1];
  const float* b1 = (const float*)d_in[2];
  const float* w2 = (const float*)d_in[3];
  const float* b2 = (const float*)d_in[4];
  const float* w3 = (const float*)d_in[5];
  const float* b3 = (const float*)d_in[6];
  const float* mu = (const float*)d_in[7];
  const float* label = (const float*)d_in[8];
  float* out = (float*)d_out;

  char* ws = (char*)d_ws;
  _Float16* w1r  = (_Float16*)(ws + OFF_W1R);
  _Float16* w2r  = (_Float16*)(ws + OFF_W2R);
  float*    wmu2 = (float*)   (ws + OFF_WMU);
  float*    lgb  = (float*)   (ws + OFF_LGB);
  _Float16* act0 = (_Float16*)(ws + OFF_ACT0);   // [4][HW][64], 32 MB
  _Float16* act1 = (_Float16*)(ws + OFF_ACT1);   // [4][HW][256], 128 MB
  float*    wpart = (float*)  (ws + OFF_ACT1);   // 131 KB, dead before conv1

  // act2(b) destinations: all in regions dead at time of write
  _Float16* a2d[4] = {
    (_Float16*)(ws + OFF_ACT0),                          // b=0: act0 (dead)
    act1 + 0 * (size_t)65536 * 256,                      // b=1: act1[0] (dead)
    act1 + 1 * (size_t)65536 * 256,                      // b=2: act1[1] (dead)
    act1 + 2 * (size_t)65536 * 256                       // b=3: act1[2] (dead)
  };

  k_prep<<<3024, 256, 0, stream>>>(w1, w2, w3, b3, mu, w1r, w2r, wpart, lgb);
  k_prep2<<<16, 256, 0, stream>>>(wpart, wmu2);
  k_t0<<<4096, 256, 0, stream>>>(x, act0);
  k_conv<64><<<2048, 256, 0, stream>>>(act0, (const char*)w1r, b1, act1);
  for (int b = 0; b < BB; ++b)
    k_conv<256><<<512, 256, 0, stream>>>(act1 + (size_t)b * 65536 * 256,
                                         (const char*)w2r, b2, a2d[b]);
  k_head<<<1024, 256, 0, stream>>>(a2d[0], a2d[1], a2d[2], a2d[3],
                                   wmu2, lgb, label, out);
}

// Round 8
// 612.822 us; speedup vs baseline: 1.5716x; 1.0070x over previous
//
#include <hip/hip_runtime.h>

// Problem constants
#define BB   4
#define CIN  64
#define HH   256
#define WW   256
#define QQ   256
#define KK   16

typedef _Float16 half8 __attribute__((ext_vector_type(8)));
typedef float   f32x16 __attribute__((ext_vector_type(16)));
typedef unsigned int u32;

// ---- workspace layout (bytes); r8 proved ws_size >= 169378048 ----
#define OFF_W1R   0ull
#define OFF_W2R   294912ull
#define OFF_WMU   1474560ull
#define OFF_LGB   1490944ull
#define OFF_ACT0  1605888ull
#define OFF_ACT1  35160320ull

__device__ __forceinline__ void dma16(const void* g, void* l) {
  __builtin_amdgcn_global_load_lds(
      (const __attribute__((address_space(1))) u32*)g,
      (__attribute__((address_space(3))) u32*)l, 16, 0, 0);
}

// ---------------------------------------------------------------------------
// Prep. Blocks 0..575: w1r; 576..2879: w2r; 2880..3007: wmu2 partials;
// 3008..3023: lgb.
// NEW weight layout (global-direct B): per 16KB block (blk = cc*9+tt),
// element index = ks*4096 + n*16 + khalf*8 + e  (ks,khalf in {0,1}, e in
// 0..7, n in 0..255); source channel c = cc*32 + ks*16 + khalf*8 + e.
// A wave's fragment read (ks,nt) is then one CONTIGUOUS 1KB dwordx4:
// byte = blk*16384 + ks*8192 + (n)*32 + khalf*16.
// ---------------------------------------------------------------------------
__global__ __launch_bounds__(256) void k_prep(
    const float* __restrict__ w1, const float* __restrict__ w2,
    const float* __restrict__ w3, const float* __restrict__ b3,
    const float* __restrict__ mu,
    _Float16* __restrict__ w1r, _Float16* __restrict__ w2r,
    float* __restrict__ wpart, float* __restrict__ lgb) {
  int bid = blockIdx.x, tid = threadIdx.x;
  if (bid < 576) {                          // w1r (CI=64)
    int idx = bid * 256 + tid;
    int blk = idx >> 13;
    int cc = blk / 9, tt = blk - cc * 9;
    int rem = idx & 8191;
    int ks = rem >> 12;
    int n  = (rem >> 4) & 255;
    int kh = (rem >> 3) & 1;
    int e  = rem & 7;
    int c = cc * 32 + ks * 16 + kh * 8 + e;
    w1r[idx] = (_Float16)w1[(n * 64 + c) * 9 + tt];
  } else if (bid < 2880) {                  // w2r (CI=256)
    int d = (bid - 576) * 256 + tid;
    int blk = d >> 13;
    int cc = blk / 9, tt = blk - cc * 9;
    int rem = d & 8191;
    int ks = rem >> 12;
    int n  = (rem >> 4) & 255;
    int kh = (rem >> 3) & 1;
    int e  = rem & 7;
    int c = cc * 32 + ks * 16 + kh * 8 + e;
    w2r[d] = (_Float16)w2[(n * 256 + c) * 9 + tt];
  } else if (bid < 3008) {                  // wmu2 partials
    int j = bid - 2880;
    int k = j >> 3, o0 = (j & 7) << 5;
    float s = 0.f;
#pragma unroll 4
    for (int oi = 0; oi < 32; ++oi) {
      int o = o0 + oi;
      s = fmaf(mu[k * 256 + o], w3[o * 256 + tid], s);
    }
    wpart[j * 256 + tid] = s;
  } else {                                  // lgb, one block per k
    int k = bid - 3008;
    float m = mu[k * 256 + tid];
    __shared__ float red[256];
    red[tid] = m * (2.f * b3[tid] - m);
    __syncthreads();
    for (int st = 128; st > 0; st >>= 1) {
      if (tid < st) red[tid] += red[tid + st];
      __syncthreads();
    }
    if (tid == 0) lgb[k] = red[0];
  }
}

// Reduce wmu2 partials: wmu2[k][c] = 2 * sum_p wpart[k*8+p][c]. 16 blocks.
__global__ __launch_bounds__(256) void k_prep2(
    const float* __restrict__ wpart, float* __restrict__ wmu2) {
  int k = blockIdx.x, tid = threadIdx.x;
  float s = 0.f;
#pragma unroll
  for (int p = 0; p < 8; ++p) s += wpart[(k * 8 + p) * 256 + tid];
  wmu2[k * 256 + tid] = 2.f * s;
}

// ---------------------------------------------------------------------------
// T0: x NCHW fp32 -> act0 [b][HW][64] fp16, all 4 batches. grid 4096.
// ---------------------------------------------------------------------------
__global__ __launch_bounds__(256) void k_t0(const float* __restrict__ x,
                                            _Float16* __restrict__ act0) {
  __shared__ float tile[64][65];
  int blk = blockIdx.x;
  int b = blk >> 10;
  int p0 = (blk & 1023) << 6;
  int t = threadIdx.x;
  {
    int p = t & 63, c0 = t >> 6;
    const float* xb = x + (size_t)b * (CIN * 65536) + p0 + p;
#pragma unroll
    for (int i = 0; i < 16; ++i) {
      int c = c0 + (i << 2);
      tile[c][p] = xb[(size_t)c * 65536];
    }
  }
  __syncthreads();
  {
    _Float16* o = act0 + (size_t)(b * 65536 + p0) * CIN;
#pragma unroll
    for (int uu = 0; uu < 2; ++uu) {
      int u = t + (uu << 8);
      int px = u & 63, oct = u >> 6;
      half8 h;
#pragma unroll
      for (int i = 0; i < 8; ++i) h[i] = (_Float16)tile[oct * 8 + i][px];
      *(half8*)(o + px * CIN + oct * 8) = h;
    }
  }
}

// ---------------------------------------------------------------------------
// Conv 3x3 (replicate pad) + bias + ReLU, 32x32x16 fp16 MFMA.
//
// GLOBAL-DIRECT B (this round): weights have no intra-block reuse and are
// fully L2-resident (w1r 288KB / w2r 1.2MB shared by all blocks), so B
// skips LDS entirely. Each fragment read = one contiguous 1KB
// global_load_dwordx4 (prep's [ks][n][32B] layout). B double-buffered in
// registers (parity-named bf[u&1]; cc-pair body keeps all indices
// compile-time since 9 is odd). Consequences vs r1/r7 (93us):
//   - LDS reads 12 -> 4 b128/wave-tap (A only): LDS pillar 1150->~385cy
//   - barriers per-tap -> per-cc (A dbuf swap only): 18 -> 2 in conv<64>
//   - vmem pillar ~64KB/CU-slot of L2-hot loads ~ MFMA pillar (1033cy)
// Sync: boundary (u==8 / u==17) = s_waitcnt vmcnt(8) lgkmcnt(0) + barrier
// (8 = the just-issued next-tap B prefetch; A-DMA is older than B loads
// the compiler already waited on -> retired by FIFO). A-DMA at u==6
// (-> As[1]) and u==15 (-> As[0], if more pairs). Accumulation order
// identical to r1 -> bit-identical output.
// Epilogue: stage C-tile in LDS [px][264] fp16 (overlays As after a full
// __syncthreads), coalesced dwordx4 stores. grid 512*NB; b = blockIdx>>9.
// ---------------------------------------------------------------------------
template <int CI>
__global__ __launch_bounds__(256, 2) void k_conv(
    const _Float16* __restrict__ actin, const char* __restrict__ wr,
    const float* __restrict__ bias, _Float16* __restrict__ actout) {
  constexpr int NC = CI / 32;
  constexpr int NT = 9 * NC;
  __shared__ __align__(16) char smem[67584];   // As(2x12288) | Qs(67584)
  auto As = (char(*)[12288])smem;
  _Float16* Qs = (_Float16*)smem;              // [128][264] fp16 (epilogue)

  int tid = threadIdx.x;
  int b = blockIdx.x >> 9;
  int tile = blockIdx.x & 511;
  int txi = tile & 15, tyi = tile >> 4;
  int x0 = txi << 4, y0 = tyi << 3;
  int lane = tid & 63, wave = tid >> 6;
  int mwave = wave >> 1, nwave = wave & 1;
  int l31 = lane & 31, khalf = lane >> 5;

  f32x16 acc[2][4];
#pragma unroll
  for (int s = 0; s < 2; ++s)
#pragma unroll
    for (int nt = 0; nt < 4; ++nt)
#pragma unroll
      for (int r = 0; r < 16; ++r) acc[s][nt][r] = 0.f;

  // A staging addresses (unchanged from r1: pre-swizzled global source,
  // linear LDS dest, XOR-swizzled ds_read).
  const char* aG[3];
  int aL[3];
#pragma unroll
  for (int i = 0; i < 3; ++i) {
    int px = (wave * 3 + i) * 16 + (lane >> 2);
    int s = lane & 3;
    int pxc = min(px, 179);
    int hy = pxc / 18, hx = pxc - hy * 18;
    int y = min(max(y0 - 1 + hy, 0), 255);
    int x = min(max(x0 - 1 + hx, 0), 255);
    int q = s ^ ((pxc >> 1) & 3);
    aG[i] = (const char*)actin +
            (((size_t)(b * 65536 + y * 256 + x)) * CI + q * 8) * 2;
    aL[i] = (wave * 3 + i) * 1024;
  }

  // B global-direct per-lane pointers (ks0 / ks1), advanced 16KB per tap.
  const char* b0 = wr + ((nwave * 128 + l31) * 32 + khalf * 16);
  const char* b1 = b0 + 8192;

  // -------- prologue: A(cc=0) DMA (oldest), then preload tap0 B frags.
#pragma unroll
  for (int i = 0; i < 3; ++i) dma16(aG[i], &As[0][aL[i]]);

  half8 bf[2][2][4];   // [parity][ks][nt] — static indices after unroll
#pragma unroll
  for (int nt = 0; nt < 4; ++nt) {
    bf[0][0][nt] = *(const half8*)(b0 + nt * 1024);
    bf[0][1][nt] = *(const half8*)(b1 + nt * 1024);
  }
  b0 += 16384; b1 += 16384;
  // retire the 3 A-DMAs (8 newest = tap0 B loads may stay in flight;
  // compiler inserts the counted wait before their MFMA use).
  asm volatile("s_waitcnt vmcnt(8)" ::: "memory");
  __builtin_amdgcn_s_barrier();

  for (int c2 = 0; c2 < NC; c2 += 2) {
    bool last2 = (c2 + 2 >= NC);
#pragma unroll
    for (int u = 0; u < 18; ++u) {
      int t = (u < 9) ? u : u - 9;
      constexpr int dummy = 0; (void)dummy;
      int pr = u & 1;                       // == j&1 (c2 even)
      // ---- A prefetch (issued FIRST so it is oldest in the queue) ----
      if (u == 6) {
#pragma unroll
        for (int i = 0; i < 3; ++i)
          dma16(aG[i] + (c2 + 1) * 64, &As[1][aL[i]]);
      }
      if (u == 15 && !last2) {
#pragma unroll
        for (int i = 0; i < 3; ++i)
          dma16(aG[i] + (c2 + 2) * 64, &As[0][aL[i]]);
      }
      // ---- B prefetch for tap j+1 into parity pr^1 ----
      if (!(last2 && u == 17)) {
#pragma unroll
        for (int nt = 0; nt < 4; ++nt) {
          bf[pr ^ 1][0][nt] = *(const half8*)(b0 + nt * 1024);
          bf[pr ^ 1][1][nt] = *(const half8*)(b1 + nt * 1024);
        }
        b0 += 16384; b1 += 16384;
      }
      // ---- compute: JIT A fragment reads + 16 MFMA ----
      const char* Ab = As[(u >= 9) ? 1 : 0];
      int dy = t / 3, dx = t - dy * 3;
      half8 af[2][2];
#pragma unroll
      for (int s = 0; s < 2; ++s) {
        int px = (mwave * 4 + s * 2 + (l31 >> 4) + dy) * 18 + (l31 & 15) + dx;
        int sw = ((px >> 1) & 3) << 4;
#pragma unroll
        for (int ks = 0; ks < 2; ++ks) {
          int q = (ks * 2 + khalf) << 4;
          af[ks][s] = *(const half8*)(Ab + px * 64 + (q ^ sw));
        }
      }
      __builtin_amdgcn_s_setprio(1);
#pragma unroll
      for (int ks = 0; ks < 2; ++ks)
#pragma unroll
        for (int s = 0; s < 2; ++s)
#pragma unroll
          for (int nt = 0; nt < 4; ++nt)
            acc[s][nt] = __builtin_amdgcn_mfma_f32_32x32x16_f16(
                af[ks][s], bf[pr][ks][nt], acc[s][nt], 0, 0, 0);
      __builtin_amdgcn_s_setprio(0);
      // ---- per-cc boundary sync only ----
      if (u == 8) {
        // As[1] RAW (DMA u==6 retired: older than tap8's bf, FIFO) and
        // As[0] read-complete (lgkmcnt(0)) before u==15 overwrites it.
        asm volatile("s_waitcnt vmcnt(8) lgkmcnt(0)" ::: "memory");
        __builtin_amdgcn_s_barrier();
      }
      if (u == 17 && !last2) {
        asm volatile("s_waitcnt vmcnt(8) lgkmcnt(0)" ::: "memory");
        __builtin_amdgcn_s_barrier();
      }
    }
  }
  __syncthreads();   // WAR: epilogue Qs overlays As (all waves' reads done)

  // ---- epilogue: bias+relu, stage to LDS [px][264], coalesced stores ----
  // C/D: col = lane&31, row = (r&3) + 8*(r>>2) + 4*(lane>>5)
#pragma unroll
  for (int s = 0; s < 2; ++s)
#pragma unroll
    for (int nt = 0; nt < 4; ++nt) {
      int n = nwave * 128 + nt * 32 + l31;
      float bn = bias[n];
#pragma unroll
      for (int r = 0; r < 16; ++r) {
        int mrow = (r & 3) + 8 * (r >> 2) + 4 * khalf;
        int p = (mwave * 4 + s * 2 + (mrow >> 4)) * 16 + (mrow & 15);
        Qs[p * 264 + n] = (_Float16)fmaxf(acc[s][nt][r] + bn, 0.f);
      }
    }
  __syncthreads();
  {
    _Float16* gout = actout + (((size_t)(b * 65536 + y0 * 256 + x0)) << 8);
#pragma unroll
    for (int i = 0; i < 16; ++i) {
      int f = tid + (i << 8);
      int p = f >> 5, o = f & 31;
      half8 v = *(const half8*)&Qs[p * 264 + o * 8];
      *(half8*)(gout + (((p >> 4) * 256 + (p & 15)) << 8) + o * 8) = v;
    }
  }
}

// ---------------------------------------------------------------------------
// Head, all 4 batches in one dispatch. One px per thread, all fp32 VALU;
// wmu2/lgb/label wave-uniform -> scalar loads. grid 1024.
// ---------------------------------------------------------------------------
__global__ __launch_bounds__(256) void k_head(
    const _Float16* __restrict__ a2_0, const _Float16* __restrict__ a2_1,
    const _Float16* __restrict__ a2_2, const _Float16* __restrict__ a2_3,
    const float* __restrict__ wmu2, const float* __restrict__ lgb,
    const float* __restrict__ label, float* __restrict__ out) {
  int b = blockIdx.x >> 8;
  int px = (blockIdx.x & 255) * 256 + threadIdx.x;
  const _Float16* base = (b == 0) ? a2_0 : (b == 1) ? a2_1
                       : (b == 2) ? a2_2 : a2_3;
  const half8* ap = (const half8*)(base + ((size_t)px << 8));
  float cr[16];
#pragma unroll
  for (int k = 0; k < 16; ++k) cr[k] = lgb[k];
#pragma unroll 2
  for (int cc = 0; cc < 32; ++cc) {
    half8 h = ap[cc];
    float a0 = (float)h[0], a1 = (float)h[1], a2 = (float)h[2],
          a3 = (float)h[3], a4 = (float)h[4], a5 = (float)h[5],
          a6 = (float)h[6], a7 = (float)h[7];
#pragma unroll
    for (int k = 0; k < 16; ++k) {
      const float* w = wmu2 + (k << 8) + (cc << 3);
      float c0 = cr[k];
      c0 = fmaf(a0, w[0], c0);
      c0 = fmaf(a1, w[1], c0);
      c0 = fmaf(a2, w[2], c0);
      c0 = fmaf(a3, w[3], c0);
      c0 = fmaf(a4, w[4], c0);
      c0 = fmaf(a5, w[5], c0);
      c0 = fmaf(a6, w[6], c0);
      c0 = fmaf(a7, w[7], c0);
      cr[k] = c0;
    }
  }
  float mx = cr[0];
#pragma unroll
  for (int k = 1; k < 16; ++k) mx = fmaxf(mx, cr[k]);
  float num = 0.f, den = 0.f;
#pragma unroll
  for (int k = 0; k < 16; ++k) {
    float e = __expf(cr[k] - mx);
    num = fmaf(e, label[k], num);
    den += e;
  }
  out[(size_t)b * 65536 + px] = num / den;
}

// ---------------------------------------------------------------------------
extern "C" void kernel_launch(void* const* d_in, const int* in_sizes, int n_in,
                              void* d_out, int out_size, void* d_ws, size_t ws_size,
                              hipStream_t stream) {
  const float* x  = (const float*)d_in[0];
  const float* w1 = (const float*)d_in[1];
  const float* b1 = (const float*)d_in[2];
  const float* w2 = (const float*)d_in[3];
  const float* b2 = (const float*)d_in[4];
  const float* w3 = (const float*)d_in[5];
  const float* b3 = (const float*)d_in[6];
  const float* mu = (const float*)d_in[7];
  const float* label = (const float*)d_in[8];
  float* out = (float*)d_out;

  char* ws = (char*)d_ws;
  _Float16* w1r  = (_Float16*)(ws + OFF_W1R);
  _Float16* w2r  = (_Float16*)(ws + OFF_W2R);
  float*    wmu2 = (float*)   (ws + OFF_WMU);
  float*    lgb  = (float*)   (ws + OFF_LGB);
  _Float16* act0 = (_Float16*)(ws + OFF_ACT0);   // [4][HW][64], 32 MB
  _Float16* act1 = (_Float16*)(ws + OFF_ACT1);   // [4][HW][256], 128 MB
  float*    wpart = (float*)  (ws + OFF_ACT1);   // 131 KB, dead before conv1

  // act2(b) destinations: all in regions dead at time of write
  _Float16* a2d[4] = {
    (_Float16*)(ws + OFF_ACT0),                          // b=0: act0 (dead)
    act1 + 0 * (size_t)65536 * 256,                      // b=1: act1[0] (dead)
    act1 + 1 * (size_t)65536 * 256,                      // b=2: act1[1] (dead)
    act1 + 2 * (size_t)65536 * 256                       // b=3: act1[2] (dead)
  };

  k_prep<<<3024, 256, 0, stream>>>(w1, w2, w3, b3, mu, w1r, w2r, wpart, lgb);
  k_prep2<<<16, 256, 0, stream>>>(wpart, wmu2);
  k_t0<<<4096, 256, 0, stream>>>(x, act0);
  k_conv<64><<<2048, 256, 0, stream>>>(act0, (const char*)w1r, b1, act1);
  for (int b = 0; b < BB; ++b)
    k_conv<256><<<512, 256, 0, stream>>>(act1 + (size_t)b * 65536 * 256,
                                         (const char*)w2r, b2, a2d[b]);
  k_head<<<1024, 256, 0, stream>>>(a2d[0], a2d[1], a2d[2], a2d[3],
                                   wmu2, lgb, label, out);
}

// Round 9
// 575.390 us; speedup vs baseline: 1.6739x; 1.0651x over previous
//
#include <hip/hip_runtime.h>

// Problem constants
#define BB   4
#define CIN  64
#define HH   256
#define WW   256
#define QQ   256
#define KK   16

typedef _Float16 half8 __attribute__((ext_vector_type(8)));
typedef float   f32x16 __attribute__((ext_vector_type(16)));
typedef unsigned int u32;

// ---- workspace layout (bytes); r8 proved ws_size >= 169378048 ----
#define OFF_W1R   0ull
#define OFF_W2R   294912ull
#define OFF_WMU   1474560ull
#define OFF_LGB   1490944ull
#define OFF_ACT0  1605888ull
#define OFF_ACT1  35160320ull

__device__ __forceinline__ void dma16(const void* g, void* l) {
  __builtin_amdgcn_global_load_lds(
      (const __attribute__((address_space(1))) u32*)g,
      (__attribute__((address_space(3))) u32*)l, 16, 0, 0);
}

// ---------------------------------------------------------------------------
// Prep. Blocks 0..575: w1r; 576..2879: w2r; 2880..3007: wmu2 partials;
// 3008..3023: lgb.
// Weight layout (global-direct B): per 16KB block (blk = cc*9+tt),
// element index = ks*4096 + n*16 + khalf*8 + e; source channel
// c = cc*32 + ks*16 + khalf*8 + e. A wave's fragment read (ks,nt) is one
// CONTIGUOUS 1KB dwordx4: byte = blk*16384 + ks*8192 + n*32 + khalf*16.
// ---------------------------------------------------------------------------
__global__ __launch_bounds__(256) void k_prep(
    const float* __restrict__ w1, const float* __restrict__ w2,
    const float* __restrict__ w3, const float* __restrict__ b3,
    const float* __restrict__ mu,
    _Float16* __restrict__ w1r, _Float16* __restrict__ w2r,
    float* __restrict__ wpart, float* __restrict__ lgb) {
  int bid = blockIdx.x, tid = threadIdx.x;
  if (bid < 576) {                          // w1r (CI=64)
    int idx = bid * 256 + tid;
    int blk = idx >> 13;
    int cc = blk / 9, tt = blk - cc * 9;
    int rem = idx & 8191;
    int ks = rem >> 12;
    int n  = (rem >> 4) & 255;
    int kh = (rem >> 3) & 1;
    int e  = rem & 7;
    int c = cc * 32 + ks * 16 + kh * 8 + e;
    w1r[idx] = (_Float16)w1[(n * 64 + c) * 9 + tt];
  } else if (bid < 2880) {                  // w2r (CI=256)
    int d = (bid - 576) * 256 + tid;
    int blk = d >> 13;
    int cc = blk / 9, tt = blk - cc * 9;
    int rem = d & 8191;
    int ks = rem >> 12;
    int n  = (rem >> 4) & 255;
    int kh = (rem >> 3) & 1;
    int e  = rem & 7;
    int c = cc * 32 + ks * 16 + kh * 8 + e;
    w2r[d] = (_Float16)w2[(n * 256 + c) * 9 + tt];
  } else if (bid < 3008) {                  // wmu2 partials
    int j = bid - 2880;
    int k = j >> 3, o0 = (j & 7) << 5;
    float s = 0.f;
#pragma unroll 4
    for (int oi = 0; oi < 32; ++oi) {
      int o = o0 + oi;
      s = fmaf(mu[k * 256 + o], w3[o * 256 + tid], s);
    }
    wpart[j * 256 + tid] = s;
  } else {                                  // lgb, one block per k
    int k = bid - 3008;
    float m = mu[k * 256 + tid];
    __shared__ float red[256];
    red[tid] = m * (2.f * b3[tid] - m);
    __syncthreads();
    for (int st = 128; st > 0; st >>= 1) {
      if (tid < st) red[tid] += red[tid + st];
      __syncthreads();
    }
    if (tid == 0) lgb[k] = red[0];
  }
}

// Reduce wmu2 partials: wmu2[k][c] = 2 * sum_p wpart[k*8+p][c]. 16 blocks.
__global__ __launch_bounds__(256) void k_prep2(
    const float* __restrict__ wpart, float* __restrict__ wmu2) {
  int k = blockIdx.x, tid = threadIdx.x;
  float s = 0.f;
#pragma unroll
  for (int p = 0; p < 8; ++p) s += wpart[(k * 8 + p) * 256 + tid];
  wmu2[k * 256 + tid] = 2.f * s;
}

// ---------------------------------------------------------------------------
// T0: x NCHW fp32 -> act0 [b][HW][64] fp16, all 4 batches. grid 4096.
// ---------------------------------------------------------------------------
__global__ __launch_bounds__(256) void k_t0(const float* __restrict__ x,
                                            _Float16* __restrict__ act0) {
  __shared__ float tile[64][65];
  int blk = blockIdx.x;
  int b = blk >> 10;
  int p0 = (blk & 1023) << 6;
  int t = threadIdx.x;
  {
    int p = t & 63, c0 = t >> 6;
    const float* xb = x + (size_t)b * (CIN * 65536) + p0 + p;
#pragma unroll
    for (int i = 0; i < 16; ++i) {
      int c = c0 + (i << 2);
      tile[c][p] = xb[(size_t)c * 65536];
    }
  }
  __syncthreads();
  {
    _Float16* o = act0 + (size_t)(b * 65536 + p0) * CIN;
#pragma unroll
    for (int uu = 0; uu < 2; ++uu) {
      int u = t + (uu << 8);
      int px = u & 63, oct = u >> 6;
      half8 h;
#pragma unroll
      for (int i = 0; i < 8; ++i) h[i] = (_Float16)tile[oct * 8 + i][px];
      *(half8*)(o + px * CIN + oct * 8) = h;
    }
  }
}

// ---------------------------------------------------------------------------
// Conv 3x3 (replicate pad) + bias + ReLU, 32x32x16 fp16 MFMA,
// GLOBAL-DIRECT B (r8 structure, session-best conv dispatches 92.5us).
// Main loop unchanged from r8: B fragments load register-direct from the
// L2-resident weight image (1KB contiguous dwordx4 each), double-buffered
// by parity; A staged in LDS (dbuf, DMA); 2 barriers per 18-tap cc-pair.
//
// NEW this round: conv<256> FUSES THE HEAD. The block already owns the
// full 256-ch activation for its 128 px in Qs after staging, so instead
// of storing 32MB of act2 (re-read later by k_head over HBM), the tail
// computes logits directly: waves 0-1 take ch 0-127, waves 2-3 ch 128-255
// (hf wave-uniform via readfirstlane -> wmu2 reads stay SCALAR like
// k_head's), partials meet in an 8KB LDS scratch (scr[k*128+px],
// conflict-free), then softmax over 16 clusters -> out. Kills the k_head
// dispatch (128MB HBM re-read), conv<256>'s 32MB stores and their L2
// pollution, and the a2d aliasing. Qs stride 272 for the fused read
// pattern (4-way banks); conv<64> path byte-identical to r8 (stride 264).
// ---------------------------------------------------------------------------
template <int CI>
__global__ __launch_bounds__(256, 2) void k_conv(
    const _Float16* __restrict__ actin, const char* __restrict__ wr,
    const float* __restrict__ bias, _Float16* __restrict__ actout,
    const float* __restrict__ wmu2, const float* __restrict__ lgb,
    const float* __restrict__ label, float* __restrict__ outb) {
  constexpr int NC = CI / 32;
  constexpr int NT = 9 * NC;
  constexpr int QS = (CI == 256) ? 272 : 264;          // Qs fp16 stride
  constexpr int SMEM = (CI == 256) ? 77824 : 67584;    // +8KB scr if fused
  __shared__ __align__(16) char smem[SMEM];            // As(2x12288) | Qs
  auto As = (char(*)[12288])smem;
  _Float16* Qs = (_Float16*)smem;                      // [128][QS] fp16

  int tid = threadIdx.x;
  int b = blockIdx.x >> 9;
  int tile = blockIdx.x & 511;
  int txi = tile & 15, tyi = tile >> 4;
  int x0 = txi << 4, y0 = tyi << 3;
  int lane = tid & 63, wave = tid >> 6;
  int mwave = wave >> 1, nwave = wave & 1;
  int l31 = lane & 31, khalf = lane >> 5;

  f32x16 acc[2][4];
#pragma unroll
  for (int s = 0; s < 2; ++s)
#pragma unroll
    for (int nt = 0; nt < 4; ++nt)
#pragma unroll
      for (int r = 0; r < 16; ++r) acc[s][nt][r] = 0.f;

  // A staging addresses (pre-swizzled global source, linear LDS dest,
  // XOR-swizzled ds_read).
  const char* aG[3];
  int aL[3];
#pragma unroll
  for (int i = 0; i < 3; ++i) {
    int px = (wave * 3 + i) * 16 + (lane >> 2);
    int s = lane & 3;
    int pxc = min(px, 179);
    int hy = pxc / 18, hx = pxc - hy * 18;
    int y = min(max(y0 - 1 + hy, 0), 255);
    int x = min(max(x0 - 1 + hx, 0), 255);
    int q = s ^ ((pxc >> 1) & 3);
    aG[i] = (const char*)actin +
            (((size_t)(b * 65536 + y * 256 + x)) * CI + q * 8) * 2;
    aL[i] = (wave * 3 + i) * 1024;
  }

  // B global-direct per-lane pointers (ks0 / ks1), advanced 16KB per tap.
  const char* b0 = wr + ((nwave * 128 + l31) * 32 + khalf * 16);
  const char* b1 = b0 + 8192;

  // -------- prologue: A(cc=0) DMA (oldest), then preload tap0 B frags.
#pragma unroll
  for (int i = 0; i < 3; ++i) dma16(aG[i], &As[0][aL[i]]);

  half8 bf[2][2][4];   // [parity][ks][nt] — static indices after unroll
#pragma unroll
  for (int nt = 0; nt < 4; ++nt) {
    bf[0][0][nt] = *(const half8*)(b0 + nt * 1024);
    bf[0][1][nt] = *(const half8*)(b1 + nt * 1024);
  }
  b0 += 16384; b1 += 16384;
  asm volatile("s_waitcnt vmcnt(8)" ::: "memory");
  __builtin_amdgcn_s_barrier();

  for (int c2 = 0; c2 < NC; c2 += 2) {
    bool last2 = (c2 + 2 >= NC);
#pragma unroll
    for (int u = 0; u < 18; ++u) {
      int t = (u < 9) ? u : u - 9;
      int pr = u & 1;
      // ---- A prefetch (issued FIRST so it is oldest in the queue) ----
      if (u == 6) {
#pragma unroll
        for (int i = 0; i < 3; ++i)
          dma16(aG[i] + (c2 + 1) * 64, &As[1][aL[i]]);
      }
      if (u == 15 && !last2) {
#pragma unroll
        for (int i = 0; i < 3; ++i)
          dma16(aG[i] + (c2 + 2) * 64, &As[0][aL[i]]);
      }
      // ---- B prefetch for tap j+1 into parity pr^1 ----
      if (!(last2 && u == 17)) {
#pragma unroll
        for (int nt = 0; nt < 4; ++nt) {
          bf[pr ^ 1][0][nt] = *(const half8*)(b0 + nt * 1024);
          bf[pr ^ 1][1][nt] = *(const half8*)(b1 + nt * 1024);
        }
        b0 += 16384; b1 += 16384;
      }
      // ---- compute: JIT A fragment reads + 16 MFMA ----
      const char* Ab = As[(u >= 9) ? 1 : 0];
      int dy = t / 3, dx = t - dy * 3;
      half8 af[2][2];
#pragma unroll
      for (int s = 0; s < 2; ++s) {
        int px = (mwave * 4 + s * 2 + (l31 >> 4) + dy) * 18 + (l31 & 15) + dx;
        int sw = ((px >> 1) & 3) << 4;
#pragma unroll
        for (int ks = 0; ks < 2; ++ks) {
          int q = (ks * 2 + khalf) << 4;
          af[ks][s] = *(const half8*)(Ab + px * 64 + (q ^ sw));
        }
      }
      __builtin_amdgcn_s_setprio(1);
#pragma unroll
      for (int ks = 0; ks < 2; ++ks)
#pragma unroll
        for (int s = 0; s < 2; ++s)
#pragma unroll
          for (int nt = 0; nt < 4; ++nt)
            acc[s][nt] = __builtin_amdgcn_mfma_f32_32x32x16_f16(
                af[ks][s], bf[pr][ks][nt], acc[s][nt], 0, 0, 0);
      __builtin_amdgcn_s_setprio(0);
      // ---- per-cc boundary sync only ----
      if (u == 8) {
        asm volatile("s_waitcnt vmcnt(8) lgkmcnt(0)" ::: "memory");
        __builtin_amdgcn_s_barrier();
      }
      if (u == 17 && !last2) {
        asm volatile("s_waitcnt vmcnt(8) lgkmcnt(0)" ::: "memory");
        __builtin_amdgcn_s_barrier();
      }
    }
  }
  __syncthreads();   // WAR: Qs overlays As (all waves' reads done)

  // ---- stage bias+relu'd activation tile to LDS [128][QS] fp16 ----
  // C/D: col = lane&31, row = (r&3) + 8*(r>>2) + 4*(lane>>5)
#pragma unroll
  for (int s = 0; s < 2; ++s)
#pragma unroll
    for (int nt = 0; nt < 4; ++nt) {
      int n = nwave * 128 + nt * 32 + l31;
      float bn = bias[n];
#pragma unroll
      for (int r = 0; r < 16; ++r) {
        int mrow = (r & 3) + 8 * (r >> 2) + 4 * khalf;
        int p = (mwave * 4 + s * 2 + (mrow >> 4)) * 16 + (mrow & 15);
        Qs[p * QS + n] = (_Float16)fmaxf(acc[s][nt][r] + bn, 0.f);
      }
    }
  __syncthreads();

  if (CI == 64) {
    // ---- conv1: coalesced act1 stores (identical to r8) ----
    _Float16* gout = actout + (((size_t)(b * 65536 + y0 * 256 + x0)) << 8);
#pragma unroll
    for (int i = 0; i < 16; ++i) {
      int f = tid + (i << 8);
      int p = f >> 5, o = f & 31;
      half8 v = *(const half8*)&Qs[p * QS + o * 8];
      *(half8*)(gout + (((p >> 4) * 256 + (p & 15)) << 8) + o * 8) = v;
    }
  } else {
    // ---- conv2: FUSED HEAD. waves 0-1: ch 0-127; waves 2-3: ch 128-255.
    float* scr = (float*)(smem + 69632);     // [16][128] partials, 8KB
    int hf = __builtin_amdgcn_readfirstlane(wave >> 1);  // wave-uniform
    int px = ((wave & 1) << 6) + lane;       // 0..127
    const _Float16* qrow = Qs + px * QS + hf * 128;
    float cr[16];
#pragma unroll
    for (int k = 0; k < 16; ++k) cr[k] = 0.f;
#pragma unroll 2
    for (int c8 = 0; c8 < 16; ++c8) {
      half8 h = *(const half8*)(qrow + c8 * 8);
      float a0 = (float)h[0], a1 = (float)h[1], a2 = (float)h[2],
            a3 = (float)h[3], a4 = (float)h[4], a5 = (float)h[5],
            a6 = (float)h[6], a7 = (float)h[7];
#pragma unroll
      for (int k = 0; k < 16; ++k) {
        const float* w = wmu2 + (k << 8) + (hf << 7) + (c8 << 3);  // scalar
        float c0 = cr[k];
        c0 = fmaf(a0, w[0], c0);
        c0 = fmaf(a1, w[1], c0);
        c0 = fmaf(a2, w[2], c0);
        c0 = fmaf(a3, w[3], c0);
        c0 = fmaf(a4, w[4], c0);
        c0 = fmaf(a5, w[5], c0);
        c0 = fmaf(a6, w[6], c0);
        c0 = fmaf(a7, w[7], c0);
        cr[k] = c0;
      }
    }
    if (hf) {
#pragma unroll
      for (int k = 0; k < 16; ++k) scr[k * 128 + px] = cr[k];
    }
    __syncthreads();
    if (!hf) {
#pragma unroll
      for (int k = 0; k < 16; ++k) cr[k] += scr[k * 128 + px] + lgb[k];
      float mx = cr[0];
#pragma unroll
      for (int k = 1; k < 16; ++k) mx = fmaxf(mx, cr[k]);
      float num = 0.f, den = 0.f;
#pragma unroll
      for (int k = 0; k < 16; ++k) {
        float e = __expf(cr[k] - mx);
        num = fmaf(e, label[k], num);
        den += e;
      }
      outb[(y0 + (px >> 4)) * 256 + (x0 + (px & 15))] = num / den;
    }
  }
}

// ---------------------------------------------------------------------------
extern "C" void kernel_launch(void* const* d_in, const int* in_sizes, int n_in,
                              void* d_out, int out_size, void* d_ws, size_t ws_size,
                              hipStream_t stream) {
  const float* x  = (const float*)d_in[0];
  const float* w1 = (const float*)d_in[1];
  const float* b1 = (const float*)d_in[2];
  const float* w2 = (const float*)d_in[3];
  const float* b2 = (const float*)d_in[4];
  const float* w3 = (const float*)d_in[5];
  const float* b3 = (const float*)d_in[6];
  const float* mu = (const float*)d_in[7];
  const float* label = (const float*)d_in[8];
  float* out = (float*)d_out;

  char* ws = (char*)d_ws;
  _Float16* w1r  = (_Float16*)(ws + OFF_W1R);
  _Float16* w2r  = (_Float16*)(ws + OFF_W2R);
  float*    wmu2 = (float*)   (ws + OFF_WMU);
  float*    lgb  = (float*)   (ws + OFF_LGB);
  _Float16* act0 = (_Float16*)(ws + OFF_ACT0);   // [4][HW][64], 32 MB
  _Float16* act1 = (_Float16*)(ws + OFF_ACT1);   // [4][HW][256], 128 MB
  float*    wpart = (float*)  (ws + OFF_ACT1);   // 131 KB, dead before conv1

  k_prep<<<3024, 256, 0, stream>>>(w1, w2, w3, b3, mu, w1r, w2r, wpart, lgb);
  k_prep2<<<16, 256, 0, stream>>>(wpart, wmu2);
  k_t0<<<4096, 256, 0, stream>>>(x, act0);
  k_conv<64><<<2048, 256, 0, stream>>>(act0, (const char*)w1r, b1, act1,
                                       nullptr, nullptr, nullptr, nullptr);
  for (int b = 0; b < BB; ++b)
    k_conv<256><<<512, 256, 0, stream>>>(act1 + (size_t)b * 65536 * 256,
                                         (const char*)w2r, b2, nullptr,
                                         wmu2, lgb, label,
                                         out + (size_t)b * 65536);
}

// Round 11
// 529.377 us; speedup vs baseline: 1.8193x; 1.0869x over previous
//
#include <hip/hip_runtime.h>

// Problem constants
#define BB   4
#define CIN  64
#define HH   256
#define WW   256
#define QQ   256
#define KK   16

typedef _Float16 half8 __attribute__((ext_vector_type(8)));
typedef float   f32x16 __attribute__((ext_vector_type(16)));
typedef unsigned int u32;

// ---- workspace layout (bytes); r8 proved ws_size >= 169378048 ----
#define OFF_W1R   0ull
#define OFF_W2R   294912ull
#define OFF_WMU   1474560ull
#define OFF_LGB   1490944ull
#define OFF_ACT0  1605888ull
#define OFF_ACT1  35160320ull

__device__ __forceinline__ void dma16(const void* g, void* l) {
  __builtin_amdgcn_global_load_lds(
      (const __attribute__((address_space(1))) u32*)g,
      (__attribute__((address_space(3))) u32*)l, 16, 0, 0);
}

// ---------------------------------------------------------------------------
// Prep + T0 merged (independent producers, one dispatch so their memory
// traffic overlaps). Blocks 0..575: w1r; 576..2879: w2r; 2880..3007: wmu2
// partials; 3008..3023: lgb; 3024..7119: t0 (x NCHW fp32 -> act0 fp16).
// Weight layout (global-direct B): per 16KB block (blk = cc*9+tt),
// element index = ks*4096 + n*16 + khalf*8 + e; source channel
// c = cc*32 + ks*16 + khalf*8 + e. A wave's fragment read (ks,nt) is one
// CONTIGUOUS 1KB dwordx4: byte = blk*16384 + ks*8192 + n*32 + khalf*16.
// ---------------------------------------------------------------------------
__global__ __launch_bounds__(256) void k_prep(
    const float* __restrict__ w1, const float* __restrict__ w2,
    const float* __restrict__ w3, const float* __restrict__ b3,
    const float* __restrict__ mu, const float* __restrict__ x,
    _Float16* __restrict__ w1r, _Float16* __restrict__ w2r,
    float* __restrict__ wpart, float* __restrict__ lgb,
    _Float16* __restrict__ act0) {
  __shared__ float tile[64][65];
  __shared__ float red[256];
  int bid = blockIdx.x, tid = threadIdx.x;
  if (bid < 576) {                          // w1r (CI=64)
    int idx = bid * 256 + tid;
    int blk = idx >> 13;
    int cc = blk / 9, tt = blk - cc * 9;
    int rem = idx & 8191;
    int ks = rem >> 12;
    int n  = (rem >> 4) & 255;
    int kh = (rem >> 3) & 1;
    int e  = rem & 7;
    int c = cc * 32 + ks * 16 + kh * 8 + e;
    w1r[idx] = (_Float16)w1[(n * 64 + c) * 9 + tt];
  } else if (bid < 2880) {                  // w2r (CI=256)
    int d = (bid - 576) * 256 + tid;
    int blk = d >> 13;
    int cc = blk / 9, tt = blk - cc * 9;
    int rem = d & 8191;
    int ks = rem >> 12;
    int n  = (rem >> 4) & 255;
    int kh = (rem >> 3) & 1;
    int e  = rem & 7;
    int c = cc * 32 + ks * 16 + kh * 8 + e;
    w2r[d] = (_Float16)w2[(n * 256 + c) * 9 + tt];
  } else if (bid < 3008) {                  // wmu2 partials
    int j = bid - 2880;
    int k = j >> 3, o0 = (j & 7) << 5;
    float s = 0.f;
#pragma unroll 4
    for (int oi = 0; oi < 32; ++oi) {
      int o = o0 + oi;
      s = fmaf(mu[k * 256 + o], w3[o * 256 + tid], s);
    }
    wpart[j * 256 + tid] = s;
  } else if (bid < 3024) {                  // lgb, one block per k
    int k = bid - 3008;
    float m = mu[k * 256 + tid];
    red[tid] = m * (2.f * b3[tid] - m);
    __syncthreads();
    for (int st = 128; st > 0; st >>= 1) {
      if (tid < st) red[tid] += red[tid + st];
      __syncthreads();
    }
    if (tid == 0) lgb[k] = red[0];
  } else {                                  // t0: x -> act0 [b][HW][64] fp16
    int blk = bid - 3024;
    int b = blk >> 10;
    int p0 = (blk & 1023) << 6;
    {
      int p = tid & 63, c0 = tid >> 6;
      const float* xb = x + (size_t)b * (CIN * 65536) + p0 + p;
#pragma unroll
      for (int i = 0; i < 16; ++i) {
        int c = c0 + (i << 2);
        tile[c][p] = xb[(size_t)c * 65536];
      }
    }
    __syncthreads();
    {
      _Float16* o = act0 + (size_t)(b * 65536 + p0) * CIN;
#pragma unroll
      for (int uu = 0; uu < 2; ++uu) {
        int u = tid + (uu << 8);
        int px = u & 63, oct = u >> 6;
        half8 h;
#pragma unroll
        for (int i = 0; i < 8; ++i) h[i] = (_Float16)tile[oct * 8 + i][px];
        *(half8*)(o + px * CIN + oct * 8) = h;
      }
    }
  }
}

// Reduce wmu2 partials: wmu2[k][c] = 2 * sum_p wpart[k*8+p][c]. 16 blocks.
__global__ __launch_bounds__(256) void k_prep2(
    const float* __restrict__ wpart, float* __restrict__ wmu2) {
  int k = blockIdx.x, tid = threadIdx.x;
  float s = 0.f;
#pragma unroll
  for (int p = 0; p < 8; ++p) s += wpart[(k * 8 + p) * 256 + tid];
  wmu2[k * 256 + tid] = 2.f * s;
}

// ---------------------------------------------------------------------------
// Conv 3x3 (replicate pad) + bias + ReLU, 32x32x16 fp16 MFMA,
// GLOBAL-DIRECT B (r8 structure; conv main loop at its proven plateau).
// B fragments load register-direct from the L2-resident weight image (1KB
// contiguous dwordx4 each), double-buffered by parity; A staged in LDS
// (dbuf, DMA); 2 barriers per 18-tap cc-pair.
//
// conv<256> FUSES THE HEAD (r9): waves 0-1 ch 0-127, waves 2-3 ch 128-255
// (hf wave-uniform -> scalar wmu2 loads), partials meet in 8KB LDS scr,
// softmax over 16 clusters -> out. No act2 stores at all.
//
// All 4 batches of conv<256> in ONE dispatch (2048 blocks) — with the
// fused head there is no act2->act1 aliasing, so the per-batch
// serialization was pure overhead (3 dispatch-boundary drains + 3 launch
// gaps). Identical per-block work -> bit-identical output.
// ---------------------------------------------------------------------------
template <int CI>
__global__ __launch_bounds__(256, 2) void k_conv(
    const _Float16* __restrict__ actin, const char* __restrict__ wr,
    const float* __restrict__ bias, _Float16* __restrict__ actout,
    const float* __restrict__ wmu2, const float* __restrict__ lgb,
    const float* __restrict__ label, float* __restrict__ outb) {
  constexpr int NC = CI / 32;
  constexpr int NT = 9 * NC;
  constexpr int QS = (CI == 256) ? 272 : 264;          // Qs fp16 stride
  constexpr int SMEM = (CI == 256) ? 77824 : 67584;    // +8KB scr if fused
  __shared__ __align__(16) char smem[SMEM];            // As(2x12288) | Qs
  auto As = (char(*)[12288])smem;
  _Float16* Qs = (_Float16*)smem;                      // [128][QS] fp16

  int tid = threadIdx.x;
  int b = blockIdx.x >> 9;
  int tile = blockIdx.x & 511;
  int txi = tile & 15, tyi = tile >> 4;
  int x0 = txi << 4, y0 = tyi << 3;
  int lane = tid & 63, wave = tid >> 6;
  int mwave = wave >> 1, nwave = wave & 1;
  int l31 = lane & 31, khalf = lane >> 5;

  f32x16 acc[2][4];
#pragma unroll
  for (int s = 0; s < 2; ++s)
#pragma unroll
    for (int nt = 0; nt < 4; ++nt)
#pragma unroll
      for (int r = 0; r < 16; ++r) acc[s][nt][r] = 0.f;

  // A staging addresses (pre-swizzled global source, linear LDS dest,
  // XOR-swizzled ds_read).
  const char* aG[3];
  int aL[3];
#pragma unroll
  for (int i = 0; i < 3; ++i) {
    int px = (wave * 3 + i) * 16 + (lane >> 2);
    int s = lane & 3;
    int pxc = min(px, 179);
    int hy = pxc / 18, hx = pxc - hy * 18;
    int y = min(max(y0 - 1 + hy, 0), 255);
    int x = min(max(x0 - 1 + hx, 0), 255);
    int q = s ^ ((pxc >> 1) & 3);
    aG[i] = (const char*)actin +
            (((size_t)(b * 65536 + y * 256 + x)) * CI + q * 8) * 2;
    aL[i] = (wave * 3 + i) * 1024;
  }

  // B global-direct per-lane pointers (ks0 / ks1), advanced 16KB per tap.
  const char* b0 = wr + ((nwave * 128 + l31) * 32 + khalf * 16);
  const char* b1 = b0 + 8192;

  // -------- prologue: A(cc=0) DMA (oldest), then preload tap0 B frags.
#pragma unroll
  for (int i = 0; i < 3; ++i) dma16(aG[i], &As[0][aL[i]]);

  half8 bf[2][2][4];   // [parity][ks][nt] — static indices after unroll
#pragma unroll
  for (int nt = 0; nt < 4; ++nt) {
    bf[0][0][nt] = *(const half8*)(b0 + nt * 1024);
    bf[0][1][nt] = *(const half8*)(b1 + nt * 1024);
  }
  b0 += 16384; b1 += 16384;
  asm volatile("s_waitcnt vmcnt(8)" ::: "memory");
  __builtin_amdgcn_s_barrier();

  for (int c2 = 0; c2 < NC; c2 += 2) {
    bool last2 = (c2 + 2 >= NC);
#pragma unroll
    for (int u = 0; u < 18; ++u) {
      int t = (u < 9) ? u : u - 9;
      int pr = u & 1;
      // ---- A prefetch (issued FIRST so it is oldest in the queue) ----
      if (u == 6) {
#pragma unroll
        for (int i = 0; i < 3; ++i)
          dma16(aG[i] + (c2 + 1) * 64, &As[1][aL[i]]);
      }
      if (u == 15 && !last2) {
#pragma unroll
        for (int i = 0; i < 3; ++i)
          dma16(aG[i] + (c2 + 2) * 64, &As[0][aL[i]]);
      }
      // ---- B prefetch for tap j+1 into parity pr^1 ----
      if (!(last2 && u == 17)) {
#pragma unroll
        for (int nt = 0; nt < 4; ++nt) {
          bf[pr ^ 1][0][nt] = *(const half8*)(b0 + nt * 1024);
          bf[pr ^ 1][1][nt] = *(const half8*)(b1 + nt * 1024);
        }
        b0 += 16384; b1 += 16384;
      }
      // ---- compute: JIT A fragment reads + 16 MFMA ----
      const char* Ab = As[(u >= 9) ? 1 : 0];
      int dy = t / 3, dx = t - dy * 3;
      half8 af[2][2];
#pragma unroll
      for (int s = 0; s < 2; ++s) {
        int px = (mwave * 4 + s * 2 + (l31 >> 4) + dy) * 18 + (l31 & 15) + dx;
        int sw = ((px >> 1) & 3) << 4;
#pragma unroll
        for (int ks = 0; ks < 2; ++ks) {
          int q = (ks * 2 + khalf) << 4;
          af[ks][s] = *(const half8*)(Ab + px * 64 + (q ^ sw));
        }
      }
      __builtin_amdgcn_s_setprio(1);
#pragma unroll
      for (int ks = 0; ks < 2; ++ks)
#pragma unroll
        for (int s = 0; s < 2; ++s)
#pragma unroll
          for (int nt = 0; nt < 4; ++nt)
            acc[s][nt] = __builtin_amdgcn_mfma_f32_32x32x16_f16(
                af[ks][s], bf[pr][ks][nt], acc[s][nt], 0, 0, 0);
      __builtin_amdgcn_s_setprio(0);
      // ---- per-cc boundary sync only ----
      if (u == 8) {
        asm volatile("s_waitcnt vmcnt(8) lgkmcnt(0)" ::: "memory");
        __builtin_amdgcn_s_barrier();
      }
      if (u == 17 && !last2) {
        asm volatile("s_waitcnt vmcnt(8) lgkmcnt(0)" ::: "memory");
        __builtin_amdgcn_s_barrier();
      }
    }
  }
  __syncthreads();   // WAR: Qs overlays As (all waves' reads done)

  // ---- stage bias+relu'd activation tile to LDS [128][QS] fp16 ----
  // C/D: col = lane&31, row = (r&3) + 8*(r>>2) + 4*(lane>>5)
#pragma unroll
  for (int s = 0; s < 2; ++s)
#pragma unroll
    for (int nt = 0; nt < 4; ++nt) {
      int n = nwave * 128 + nt * 32 + l31;
      float bn = bias[n];
#pragma unroll
      for (int r = 0; r < 16; ++r) {
        int mrow = (r & 3) + 8 * (r >> 2) + 4 * khalf;
        int p = (mwave * 4 + s * 2 + (mrow >> 4)) * 16 + (mrow & 15);
        Qs[p * QS + n] = (_Float16)fmaxf(acc[s][nt][r] + bn, 0.f);
      }
    }
  __syncthreads();

  if (CI == 64) {
    // ---- conv1: coalesced act1 stores ----
    _Float16* gout = actout + (((size_t)(b * 65536 + y0 * 256 + x0)) << 8);
#pragma unroll
    for (int i = 0; i < 16; ++i) {
      int f = tid + (i << 8);
      int p = f >> 5, o = f & 31;
      half8 v = *(const half8*)&Qs[p * QS + o * 8];
      *(half8*)(gout + (((p >> 4) * 256 + (p & 15)) << 8) + o * 8) = v;
    }
  } else {
    // ---- conv2: FUSED HEAD. waves 0-1: ch 0-127; waves 2-3: ch 128-255.
    float* scr = (float*)(smem + 69632);     // [16][128] partials, 8KB
    int hf = __builtin_amdgcn_readfirstlane(wave >> 1);  // wave-uniform
    int px = ((wave & 1) << 6) + lane;       // 0..127
    const _Float16* qrow = Qs + px * QS + hf * 128;
    float cr[16];
#pragma unroll
    for (int k = 0; k < 16; ++k) cr[k] = 0.f;
#pragma unroll 2
    for (int c8 = 0; c8 < 16; ++c8) {
      half8 h = *(const half8*)(qrow + c8 * 8);
      float a0 = (float)h[0], a1 = (float)h[1], a2 = (float)h[2],
            a3 = (float)h[3], a4 = (float)h[4], a5 = (float)h[5],
            a6 = (float)h[6], a7 = (float)h[7];
#pragma unroll
      for (int k = 0; k < 16; ++k) {
        const float* w = wmu2 + (k << 8) + (hf << 7) + (c8 << 3);  // scalar
        float c0 = cr[k];
        c0 = fmaf(a0, w[0], c0);
        c0 = fmaf(a1, w[1], c0);
        c0 = fmaf(a2, w[2], c0);
        c0 = fmaf(a3, w[3], c0);
        c0 = fmaf(a4, w[4], c0);
        c0 = fmaf(a5, w[5], c0);
        c0 = fmaf(a6, w[6], c0);
        c0 = fmaf(a7, w[7], c0);
        cr[k] = c0;
      }
    }
    if (hf) {
#pragma unroll
      for (int k = 0; k < 16; ++k) scr[k * 128 + px] = cr[k];
    }
    __syncthreads();
    if (!hf) {
#pragma unroll
      for (int k = 0; k < 16; ++k) cr[k] += scr[k * 128 + px] + lgb[k];
      float mx = cr[0];
#pragma unroll
      for (int k = 1; k < 16; ++k) mx = fmaxf(mx, cr[k]);
      float num = 0.f, den = 0.f;
#pragma unroll
      for (int k = 0; k < 16; ++k) {
        float e = __expf(cr[k] - mx);
        num = fmaf(e, label[k], num);
        den += e;
      }
      outb[(size_t)b * 65536 + (y0 + (px >> 4)) * 256 + (x0 + (px & 15))] =
          num / den;
    }
  }
}

// ---------------------------------------------------------------------------
extern "C" void kernel_launch(void* const* d_in, const int* in_sizes, int n_in,
                              void* d_out, int out_size, void* d_ws, size_t ws_size,
                              hipStream_t stream) {
  const float* x  = (const float*)d_in[0];
  const float* w1 = (const float*)d_in[1];
  const float* b1 = (const float*)d_in[2];
  const float* w2 = (const float*)d_in[3];
  const float* b2 = (const float*)d_in[4];
  const float* w3 = (const float*)d_in[5];
  const float* b3 = (const float*)d_in[6];
  const float* mu = (const float*)d_in[7];
  const float* label = (const float*)d_in[8];
  float* out = (float*)d_out;

  char* ws = (char*)d_ws;
  _Float16* w1r  = (_Float16*)(ws + OFF_W1R);
  _Float16* w2r  = (_Float16*)(ws + OFF_W2R);
  float*    wmu2 = (float*)   (ws + OFF_WMU);
  float*    lgb  = (float*)   (ws + OFF_LGB);
  _Float16* act0 = (_Float16*)(ws + OFF_ACT0);   // [4][HW][64], 32 MB
  _Float16* act1 = (_Float16*)(ws + OFF_ACT1);   // [4][HW][256], 128 MB
  float*    wpart = (float*)  (ws + OFF_ACT1);   // 131 KB, dead before conv1

  // prep (weights/head constants) + t0 merged: independent producers.
  k_prep<<<7120, 256, 0, stream>>>(w1, w2, w3, b3, mu, x,
                                   w1r, w2r, wpart, lgb, act0);
  k_prep2<<<16, 256, 0, stream>>>(wpart, wmu2);
  k_conv<64><<<2048, 256, 0, stream>>>(act0, (const char*)w1r, b1, act1,
                                       nullptr, nullptr, nullptr, nullptr);
  // all 4 batches in one dispatch (no act2 aliasing since head fusion)
  k_conv<256><<<2048, 256, 0, stream>>>(act1, (const char*)w2r, b2, nullptr,
                                        wmu2, lgb, label, out);
}